// Round 1
// baseline (253.887 us; speedup 1.0000x reference)
//
#include <hip/hip_runtime.h>
#include <hip/hip_bf16.h>

#define BBATCH 8
#define TSEQ   1024
#define DMODEL 1024
#define NHEAD  16
#define HSZ    64

typedef unsigned short ushort_t;
typedef __attribute__((ext_vector_type(8))) short short8;
typedef __attribute__((ext_vector_type(4))) float float4v;

__device__ __forceinline__ ushort_t f2bf(float f) {
    __hip_bfloat16 h = __float2bfloat16(f);
    return *reinterpret_cast<ushort_t*>(&h);
}
// fast fp32->bf16, round-half-up
__device__ __forceinline__ ushort_t f2bf_fast(float f) {
    return (ushort_t)((__float_as_uint(f) + 0x8000u) >> 16);
}
// pack two fp32 -> uint {bf16(lo), bf16(hi)}
__device__ __forceinline__ unsigned int pack_bf2(float lo, float hi) {
    unsigned int a = __float_as_uint(lo) + 0x8000u;
    unsigned int b = __float_as_uint(hi) + 0x8000u;
    return __builtin_amdgcn_perm(b, a, 0x07060302u);
}

__device__ __forceinline__ short8 cvt8(const float* f) {
    union { ushort_t u[8]; short8 v; } r;
    #pragma unroll
    for (int e = 0; e < 8; ++e) r.u[e] = f2bf(f[e]);
    return r.v;
}

// async global->LDS, 16B/lane; lds base wave-uniform (HW: base + lane*16)
__device__ __forceinline__ void async16(const ushort_t* g, ushort_t* l) {
    __builtin_amdgcn_global_load_lds(
        (const __attribute__((address_space(1))) unsigned int*)g,
        (__attribute__((address_space(3))) unsigned int*)l, 16, 0, 0);
}

// ---------------------------------------------------------------------------
// cvt_f32_bf16: generic fp32 -> bf16, 16 elems/thread (X, Wo)
// ---------------------------------------------------------------------------
__global__ __launch_bounds__(256) void cvt_f32_bf16(
    const float* __restrict__ src, ushort_t* __restrict__ dst)
{
    const size_t idx = ((size_t)blockIdx.x * 256 + threadIdx.x) * 16;
    float f[16];
    *(float4*)(f + 0)  = *(const float4*)(src + idx);
    *(float4*)(f + 4)  = *(const float4*)(src + idx + 4);
    *(float4*)(f + 8)  = *(const float4*)(src + idx + 8);
    *(float4*)(f + 12) = *(const float4*)(src + idx + 12);
    uint4 o0 = make_uint4(pack_bf2(f[0], f[1]),   pack_bf2(f[2], f[3]),
                          pack_bf2(f[4], f[5]),   pack_bf2(f[6], f[7]));
    uint4 o1 = make_uint4(pack_bf2(f[8], f[9]),   pack_bf2(f[10], f[11]),
                          pack_bf2(f[12], f[13]), pack_bf2(f[14], f[15]));
    *(uint4*)(dst + idx) = o0;
    *(uint4*)(dst + idx + 8) = o1;
}

// ---------------------------------------------------------------------------
// pack_w: WpackT[w*1024 + h*64 + s][d] = W_w[h][d][s]  (fp32 -> bf16, n-major)
// ---------------------------------------------------------------------------
__global__ __launch_bounds__(256) void pack_w(
    const float* __restrict__ Wq, const float* __restrict__ Wk,
    const float* __restrict__ Wv, ushort_t* __restrict__ WpT)
{
    __shared__ ushort_t L[64 * 72];
    const int tid = threadIdx.x;
    const int d0 = blockIdx.x * 64;
    const int wh = blockIdx.y;
    const int w = wh >> 4, h = wh & 15;
    const float* W = (w == 0 ? Wq : (w == 1 ? Wk : Wv)) + (size_t)h * DMODEL * HSZ;

    int dr = tid >> 2, sc = (tid & 3) * 16;
    const float4* src = (const float4*)(W + (size_t)(d0 + dr) * HSZ + sc);
    float f[16];
    *(float4*)(f + 0) = src[0]; *(float4*)(f + 4) = src[1];
    *(float4*)(f + 8) = src[2]; *(float4*)(f + 12) = src[3];
    *(short8*)(L + dr * 72 + sc)     = cvt8(f);
    *(short8*)(L + dr * 72 + sc + 8) = cvt8(f + 8);
    __syncthreads();

    int s = tid >> 2, dc = (tid & 3) * 16;
    union { ushort_t u[16]; short8 v[2]; } o;
    #pragma unroll
    for (int j = 0; j < 16; ++j) o.u[j] = L[(dc + j) * 72 + s];
    ushort_t* dst = WpT + (size_t)(w * 1024 + h * 64 + s) * DMODEL + d0 + dc;
    *(short8*)dst = o.v[0];
    *(short8*)(dst + 8) = o.v[1];
}

// ---------------------------------------------------------------------------
// qkv_gemm: 256x256 tile, BK=64, 8 waves (2x4), double-buffered LDS,
// 4-phase-per-K-tile schedule with counted vmcnt (T3+T4) + setprio (T5) +
// XOR-8 LDS swizzle (T2) + per-XCD m-banding (T1).
//
// Per K-tile (4 phases, 16 MFMA each):
//   ph0: ds_read A(a0-3) + B(b0-1) | bar | MFMA a0-3 x b0-1 | bar
//   ph1: ds_read A(a4-7)           | bar | MFMA a4-7 x b0-1 | bar
//   ph2: ds_read B(b2-3)           | bar | MFMA a0-3 x b2-3 | bar
//   ph3: stage kt+2 (8 loads, same buffer - all reads done by ph2 barrier)
//        | bar | MFMA a4-7 x b2-3 | s_waitcnt vmcnt(8) | bar
// vmcnt(8): 16 outstanding (kt+1's 8 + kt+2's 8) -> wait oldest 8 (kt+1)
// so next tile is ready; kt+2's loads ride ~4 phases of MFMA cover.
//
// QK blocks stage WpT rows as the MFMA row operand (out rows = s -> packed
// 8B stores to Qb/Kb[bh][t][s]); V blocks stage Xb rows (out rows = t ->
// packed 8B stores direct to Vt[bh][s][t]). Q pre-scaled by 0.125*log2(e).
// Grid 384 = 8 XCD * (32 QK + 16 V) blocks; per-XCD 4-m-tile band (2MB X).
// ---------------------------------------------------------------------------
template<bool STG, int VW>
__device__ __forceinline__ void ktile_step(
    ushort_t* As, ushort_t* Bs,
    const ushort_t* (&gA)[4], const ushort_t* (&gB)[4],
    const int wave,
    const int aoff0, const int aoff1, const int boff0, const int boff1,
    float4v (&acc)[8][4])
{
    short8 avA[4][2], avB[4][2], bv[2][2];

    // ---- phase 0: read A a0-3 (both k-halves) + B b0-1; MFMA a0-3 x b0-1
    #pragma unroll
    for (int a = 0; a < 4; ++a) {
        avA[a][0] = *(const short8*)(As + aoff0 + a * 1024);
        avA[a][1] = *(const short8*)(As + aoff1 + a * 1024);
    }
    #pragma unroll
    for (int b = 0; b < 2; ++b) {
        bv[b][0] = *(const short8*)(Bs + boff0 + b * 1024);
        bv[b][1] = *(const short8*)(Bs + boff1 + b * 1024);
    }
    __builtin_amdgcn_s_barrier();
    __builtin_amdgcn_s_setprio(1);
    #pragma unroll
    for (int kth = 0; kth < 2; ++kth)
        #pragma unroll
        for (int a = 0; a < 4; ++a)
            #pragma unroll
            for (int b = 0; b < 2; ++b)
                acc[a][b] = __builtin_amdgcn_mfma_f32_16x16x32_bf16(
                    avA[a][kth], bv[b][kth], acc[a][b], 0, 0, 0);
    __builtin_amdgcn_s_setprio(0);
    __builtin_amdgcn_s_barrier();

    // ---- phase 1: read A a4-7; MFMA a4-7 x b0-1
    #pragma unroll
    for (int a = 0; a < 4; ++a) {
        avB[a][0] = *(const short8*)(As + aoff0 + (a + 4) * 1024);
        avB[a][1] = *(const short8*)(As + aoff1 + (a + 4) * 1024);
    }
    __builtin_amdgcn_s_barrier();
    __builtin_amdgcn_s_setprio(1);
    #pragma unroll
    for (int kth = 0; kth < 2; ++kth)
        #pragma unroll
        for (int a = 0; a < 4; ++a)
            #pragma unroll
            for (int b = 0; b < 2; ++b)
                acc[a + 4][b] = __builtin_amdgcn_mfma_f32_16x16x32_bf16(
                    avB[a][kth], bv[b][kth], acc[a + 4][b], 0, 0, 0);
    __builtin_amdgcn_s_setprio(0);
    __builtin_amdgcn_s_barrier();

    // ---- phase 2: read B b2-3 (reuse bv regs, b0-1 dead); MFMA a0-3 x b2-3
    #pragma unroll
    for (int b = 0; b < 2; ++b) {
        bv[b][0] = *(const short8*)(Bs + boff0 + (b + 2) * 1024);
        bv[b][1] = *(const short8*)(Bs + boff1 + (b + 2) * 1024);
    }
    __builtin_amdgcn_s_barrier();
    __builtin_amdgcn_s_setprio(1);
    #pragma unroll
    for (int kth = 0; kth < 2; ++kth)
        #pragma unroll
        for (int a = 0; a < 4; ++a)
            #pragma unroll
            for (int b = 0; b < 2; ++b)
                acc[a][b + 2] = __builtin_amdgcn_mfma_f32_16x16x32_bf16(
                    avA[a][kth], bv[b][kth], acc[a][b + 2], 0, 0, 0);
    __builtin_amdgcn_s_setprio(0);
    __builtin_amdgcn_s_barrier();

    // ---- phase 3: stage kt+2 into THIS buffer (all reads of it completed
    // by the phase-2 barrier); MFMA a4-7 x b2-3; counted vmcnt; barrier.
    if (STG) {
        #pragma unroll
        for (int i = 0; i < 4; ++i) {
            async16(gA[i], As + i * 4096 + wave * 512);
            async16(gB[i], Bs + i * 4096 + wave * 512);
            gA[i] += 64; gB[i] += 64;
        }
    }
    __builtin_amdgcn_s_barrier();
    __builtin_amdgcn_s_setprio(1);
    #pragma unroll
    for (int kth = 0; kth < 2; ++kth)
        #pragma unroll
        for (int a = 0; a < 4; ++a)
            #pragma unroll
            for (int b = 0; b < 2; ++b)
                acc[a + 4][b + 2] = __builtin_amdgcn_mfma_f32_16x16x32_bf16(
                    avB[a][kth], bv[b][kth], acc[a + 4][b + 2], 0, 0, 0);
    __builtin_amdgcn_s_setprio(0);
    if (VW == 8)      asm volatile("s_waitcnt vmcnt(8)" ::: "memory");
    else if (VW == 0) asm volatile("s_waitcnt vmcnt(0)" ::: "memory");
    __builtin_amdgcn_s_barrier();
}

__global__ __launch_bounds__(512, 2) void qkv_gemm(
    const ushort_t* __restrict__ Xb, const ushort_t* __restrict__ WpT,
    ushort_t* __restrict__ Qb, ushort_t* __restrict__ Kb, ushort_t* __restrict__ Vt)
{
    __shared__ ushort_t As0[256 * 64];
    __shared__ ushort_t Bs0[256 * 64];
    __shared__ ushort_t As1[256 * 64];
    __shared__ ushort_t Bs1[256 * 64];

    const int tid = threadIdx.x;
    const int wave = tid >> 6, lane = tid & 63;
    const int q = lane >> 4, cc = lane & 15;
    const int wm = wave >> 2, wn = wave & 3;

    // block -> tile: per-XCD 48 blocks = 32 QK (tn 0-7 x 4 m-tiles) + 16 V
    const int bid = blockIdx.x;
    const int xcd = bid & 7, lo = bid >> 3;
    const bool isV = (lo >= 32);
    int tn, tm;
    if (!isV) { tn = lo >> 2;        tm = xcd * 4 + (lo & 3); }
    else      { int v = lo - 32; tn = v >> 2; tm = xcd * 4 + (v & 3); }
    const int n0 = (isV ? 2048 : 0) + tn * 256;   // row range in WpT space
    const int m0 = tm * 256;                      // row range in Xb space

    // MFMA row operand (staged in As): weights for QK, X for V
    const ushort_t* pA = isV ? Xb + (size_t)m0 * DMODEL : WpT + (size_t)n0 * DMODEL;
    const ushort_t* pB = isV ? WpT + (size_t)n0 * DMODEL : Xb + (size_t)m0 * DMODEL;

    // staging addresses: instance i covers rows [i*64, i*64+64); XOR-8 source
    // swizzle so linear LDS dest holds LDS[row][g] = glob[row][g ^ (row&7)]
    const int srow = lane >> 3;
    const int chx = (lane & 7) ^ srow;
    const ushort_t* gA[4]; const ushort_t* gB[4];
    #pragma unroll
    for (int i = 0; i < 4; ++i) {
        int row = i * 64 + wave * 8 + srow;
        gA[i] = pA + (size_t)row * DMODEL + chx * 8;
        gB[i] = pB + (size_t)row * DMODEL + chx * 8;
    }

    // ds_read offsets (elements); row&7 == cc&7 for all fragments
    const int c7 = cc & 7;
    const int arow = wm * 128 + cc;
    const int brow = wn * 64 + cc;
    const int aoff0 = arow * 64 + ((q ^ c7) * 8);
    const int aoff1 = arow * 64 + (((4 + q) ^ c7) * 8);
    const int boff0 = brow * 64 + ((q ^ c7) * 8);
    const int boff1 = brow * 64 + (((4 + q) ^ c7) * 8);

    float4v acc[8][4];
    #pragma unroll
    for (int a = 0; a < 8; ++a)
        #pragma unroll
        for (int b = 0; b < 4; ++b) acc[a][b] = (float4v){0.f, 0.f, 0.f, 0.f};

    // prologue: stage kt0 -> buf0, kt1 -> buf1; wait kt0 (8 still in flight)
    #pragma unroll
    for (int i = 0; i < 4; ++i) {
        async16(gA[i], As0 + i * 4096 + wave * 512);
        async16(gB[i], Bs0 + i * 4096 + wave * 512);
        gA[i] += 64; gB[i] += 64;
    }
    #pragma unroll
    for (int i = 0; i < 4; ++i) {
        async16(gA[i], As1 + i * 4096 + wave * 512);
        async16(gB[i], Bs1 + i * 4096 + wave * 512);
        gA[i] += 64; gB[i] += 64;
    }
    asm volatile("s_waitcnt vmcnt(8)" ::: "memory");
    __builtin_amdgcn_s_barrier();

    // 16 K-tiles: kt 0..13 stage kt+2 & wait(8); kt14 wait(0); kt15 plain
    #pragma unroll 1
    for (int it = 0; it < 7; ++it) {
        ktile_step<true, 8>(As0, Bs0, gA, gB, wave, aoff0, aoff1, boff0, boff1, acc);
        ktile_step<true, 8>(As1, Bs1, gA, gB, wave, aoff0, aoff1, boff0, boff1, acc);
    }
    ktile_step<false, 0>(As0, Bs0, gA, gB, wave, aoff0, aoff1, boff0, boff1, acc);
    ktile_step<false, -1>(As1, Bs1, gA, gB, wave, aoff0, aoff1, boff0, boff1, acc);

    // epilogue: packed 8B stores, layouts identical to previous kernel
    if (!isV) {
        ushort_t* Out = (n0 < 1024) ? Qb : Kb;
        const float osc = (n0 < 1024) ? 0.18033688011112042f : 1.0f;
        #pragma unroll
        for (int a = 0; a < 8; ++a) {
            int nr = n0 + wm * 128 + a * 16 + q * 4;     // s-dim (rows)
            int h = (nr >> 6) & 15, s0 = nr & 63;
            #pragma unroll
            for (int b = 0; b < 4; ++b) {
                int mc = m0 + wn * 64 + b * 16 + cc;     // t-dim (cols)
                int bb = mc >> 10, t = mc & 1023;
                size_t addr = (((size_t)(bb * NHEAD + h)) * TSEQ + t) * HSZ + s0;
                uint2 pk = make_uint2(
                    pack_bf2(acc[a][b][0] * osc, acc[a][b][1] * osc),
                    pack_bf2(acc[a][b][2] * osc, acc[a][b][3] * osc));
                *(uint2*)(Out + addr) = pk;
            }
        }
    } else {
        #pragma unroll
        for (int a = 0; a < 8; ++a) {
            int mr = m0 + wm * 128 + a * 16 + q * 4;     // t-dim (rows)
            int bb = mr >> 10, t0 = mr & 1023;
            #pragma unroll
            for (int b = 0; b < 4; ++b) {
                int nc = n0 + wn * 64 + b * 16 + cc;     // s-dim (cols)
                int h = (nc >> 6) & 15, s = nc & 63;
                size_t addr = (((size_t)(bb * NHEAD + h)) * HSZ + s) * TSEQ + t0;
                uint2 pk = make_uint2(pack_bf2(acc[a][b][0], acc[a][b][1]),
                                      pack_bf2(acc[a][b][2], acc[a][b][3]));
                *(uint2*)(Vt + addr) = pk;
            }
        }
    }
}

// ---------------------------------------------------------------------------
// attn: flash attention, Q-tile 128, KV-tile 64, dbuf DMA prefetch, exp2
// softmax without running max; causal mask only on the 2 diagonal jt-tiles
// (wave-uniform branch). 1-D grid 1024, bid&7 == bh&7 -> per-bh KV co-XCD.
// ---------------------------------------------------------------------------
__global__ __launch_bounds__(256) void attn(
    const ushort_t* __restrict__ Qb, const ushort_t* __restrict__ Kb,
    const ushort_t* __restrict__ Vt, ushort_t* __restrict__ Ob)
{
    __shared__ ushort_t Ks[2][64 * 64];
    __shared__ ushort_t VTs[2][64 * 64];
    __shared__ ushort_t Ps[4][32 * 72];
    const int tid = threadIdx.x;
    const int wave = tid >> 6, lane = tid & 63;
    const int q = lane >> 4, cc = lane & 15;
    const int bid = blockIdx.x;
    const int qt = 7 - (bid >> 7);    // big-J blocks first
    const int bh = bid & 127;
    const size_t base = (size_t)bh * TSEQ * HSZ;
    const int J = 2 * qt + 2;

    const ushort_t* kg[2]; const ushort_t* vg[2]; int dmo[2];
    #pragma unroll
    for (int i = 0; i < 2; ++i) {
        int rr = wave * 16 + i * 8 + (lane >> 3);
        int ch = (lane & 7) ^ (rr & 7);
        kg[i] = Kb + base + (size_t)rr * HSZ + ch * 8;
        vg[i] = Vt + base + (size_t)rr * TSEQ + ch * 8;
        dmo[i] = (wave * 16 + i * 8) * 64;
    }

    short8 qf[2][2];
    #pragma unroll
    for (int tt = 0; tt < 2; ++tt) {
        const ushort_t* qp = Qb + base +
            (size_t)(qt * 128 + wave * 32 + tt * 16 + cc) * HSZ + q * 8;
        qf[tt][0] = *(const short8*)qp;
        qf[tt][1] = *(const short8*)(qp + 32);
    }

    int koff[4][2], poff[2][2];
    #pragma unroll
    for (int ut = 0; ut < 4; ++ut)
        #pragma unroll
        for (int kt = 0; kt < 2; ++kt)
            koff[ut][kt] = (ut * 16 + cc) * 64 + (((kt * 4 + q) ^ (cc & 7)) * 8);
    #pragma unroll
    for (int tt = 0; tt < 2; ++tt)
        #pragma unroll
        for (int kt = 0; kt < 2; ++kt)
            poff[tt][kt] = (tt * 16 + cc) * 72 + kt * 32 + q * 8;

    float4v oacc[2][4];
    #pragma unroll
    for (int tt = 0; tt < 2; ++tt)
        #pragma unroll
        for (int st = 0; st < 4; ++st) oacc[tt][st] = (float4v){0.f, 0.f, 0.f, 0.f};
    float lsum[2] = {0.f, 0.f};

    #pragma unroll
    for (int i = 0; i < 2; ++i) {
        async16(kg[i], &Ks[0][dmo[i]]);
        async16(vg[i], &VTs[0][dmo[i]]);
    }
    __syncthreads();

    for (int jt = 0; jt < J; ++jt) {
        const ushort_t* Kc = Ks[jt & 1];
        const ushort_t* Vc = VTs[jt & 1];
        if (jt + 1 < J) {
            int nb = (jt + 1) & 1;
            #pragma unroll
            for (int i = 0; i < 2; ++i) {
                async16(kg[i] + (size_t)(jt + 1) * 64 * HSZ, &Ks[nb][dmo[i]]);
                async16(vg[i] + (jt + 1) * 64, &VTs[nb][dmo[i]]);
            }
        }

        float4v sc[4][2];
        #pragma unroll
        for (int ut = 0; ut < 4; ++ut)
            #pragma unroll
            for (int tt = 0; tt < 2; ++tt) sc[ut][tt] = (float4v){0.f, 0.f, 0.f, 0.f};
        #pragma unroll
        for (int kt = 0; kt < 2; ++kt) {
            short8 kf[4];
            #pragma unroll
            for (int ut = 0; ut < 4; ++ut) kf[ut] = *(const short8*)(Kc + koff[ut][kt]);
            #pragma unroll
            for (int ut = 0; ut < 4; ++ut) {
                sc[ut][0] = __builtin_amdgcn_mfma_f32_16x16x32_bf16(
                    kf[ut], qf[0][kt], sc[ut][0], 0, 0, 0);
                sc[ut][1] = __builtin_amdgcn_mfma_f32_16x16x32_bf16(
                    kf[ut], qf[1][kt], sc[ut][1], 0, 0, 0);
            }
        }

        if ((jt >> 1) == qt) {   // diagonal tiles: masked path
            #pragma unroll
            for (int tt = 0; tt < 2; ++tt) {
                const int tg = qt * 128 + wave * 32 + tt * 16 + cc;
                #pragma unroll
                for (int ut = 0; ut < 4; ++ut) {
                    float pv[4]; float ps = 0.f;
                    #pragma unroll
                    for (int rr = 0; rr < 4; ++rr) {
                        float p = exp2f(sc[ut][tt][rr]);
                        if ((jt * 64 + ut * 16 + q * 4 + rr) > tg) p = 0.f;
                        pv[rr] = p; ps += p;
                    }
                    lsum[tt] += ps;
                    *(uint2*)&Ps[wave][(tt * 16 + cc) * 72 + ut * 16 + q * 4] =
                        make_uint2(pack_bf2(pv[0], pv[1]), pack_bf2(pv[2], pv[3]));
                }
            }
        } else {                 // interior tiles: no mask
            #pragma unroll
            for (int tt = 0; tt < 2; ++tt) {
                #pragma unroll
                for (int ut = 0; ut < 4; ++ut) {
                    float pv[4]; float ps = 0.f;
                    #pragma unroll
                    for (int rr = 0; rr < 4; ++rr) {
                        float p = exp2f(sc[ut][tt][rr]);
                        pv[rr] = p; ps += p;
                    }
                    lsum[tt] += ps;
                    *(uint2*)&Ps[wave][(tt * 16 + cc) * 72 + ut * 16 + q * 4] =
                        make_uint2(pack_bf2(pv[0], pv[1]), pack_bf2(pv[2], pv[3]));
                }
            }
        }

        #pragma unroll
        for (int kt = 0; kt < 2; ++kt) {
            short8 pa0 = *(const short8*)&Ps[wave][poff[0][kt]];
            short8 pa1 = *(const short8*)&Ps[wave][poff[1][kt]];
            #pragma unroll
            for (int st = 0; st < 4; ++st) {
                short8 vf = *(const short8*)(Vc + koff[st][kt]);
                oacc[0][st] = __builtin_amdgcn_mfma_f32_16x16x32_bf16(
                    pa0, vf, oacc[0][st], 0, 0, 0);
                oacc[1][st] = __builtin_amdgcn_mfma_f32_16x16x32_bf16(
                    pa1, vf, oacc[1][st], 0, 0, 0);
            }
        }
        __syncthreads();
    }

    float inv[2];
    #pragma unroll
    for (int tt = 0; tt < 2; ++tt) {
        float l = lsum[tt];
        l += __shfl_xor(l, 16);
        l += __shfl_xor(l, 32);
        inv[tt] = 1.f / l;
    }
    const int b = bh >> 4, h = bh & 15;
    #pragma unroll
    for (int tt = 0; tt < 2; ++tt)
        #pragma unroll
        for (int rr = 0; rr < 4; ++rr) {
            float iv = __shfl(inv[tt], q * 4 + rr);
            int t = qt * 128 + wave * 32 + tt * 16 + q * 4 + rr;
            size_t rb = ((size_t)b * TSEQ + t) * DMODEL + h * HSZ;
            #pragma unroll
            for (int st = 0; st < 4; ++st)
                Ob[rb + st * 16 + cc] = f2bf_fast(oacc[tt][st][rr] * iv);
        }
}

// ---------------------------------------------------------------------------
// oproj_gemm: out[m][n] = sum_k Ob[m][k]*Wob[n][k] + bo[n]. m97 structure.
// XCD m-banding: per-XCD 8 m-blocks (2 MB Ob) + Wob 2 MB -> 4 MB, L2-resident.
// grid 512.
// ---------------------------------------------------------------------------
__global__ __launch_bounds__(256) void oproj_gemm(
    const ushort_t* __restrict__ Obuf, const ushort_t* __restrict__ Wob,
    const float* __restrict__ bo, float* __restrict__ out)
{
    __shared__ ushort_t As[128 * 64];
    __shared__ ushort_t Bs[128 * 64];
    const int tid = threadIdx.x;
    const int wave = tid >> 6, lane = tid & 63;
    const int q = lane >> 4, cc = lane & 15;
    const int bid = blockIdx.x;
    const int xcd = bid & 7, local = bid >> 3;
    const int n0 = (local >> 3) * 128;
    const int m0 = (xcd * 8 + (local & 7)) * 128;
    const int wm = wave >> 1, wn = wave & 1;

    const ushort_t* ag[4]; const ushort_t* bg[4]; int lo_[4];
    #pragma unroll
    for (int i = 0; i < 4; ++i) {
        int row = wave * 32 + i * 8 + (lane >> 3);
        int ch = (lane & 7) ^ (row & 7);
        ag[i] = Obuf + (size_t)(m0 + row) * DMODEL + ch * 8;
        bg[i] = Wob + (size_t)(n0 + row) * DMODEL + ch * 8;
        lo_[i] = (wave * 32 + i * 8) * 64;
    }
    int aoff[4][2], boff[4][2];
    #pragma unroll
    for (int mt = 0; mt < 4; ++mt) {
        int row = wm * 64 + mt * 16 + cc;
        #pragma unroll
        for (int kt = 0; kt < 2; ++kt)
            aoff[mt][kt] = row * 64 + (((kt * 4 + q) ^ (row & 7)) * 8);
    }
    #pragma unroll
    for (int nt = 0; nt < 4; ++nt) {
        int row = wn * 64 + nt * 16 + cc;
        #pragma unroll
        for (int kt = 0; kt < 2; ++kt)
            boff[nt][kt] = row * 64 + (((kt * 4 + q) ^ (row & 7)) * 8);
    }

    float4v acc[4][4];
    #pragma unroll
    for (int a = 0; a < 4; ++a)
        #pragma unroll
        for (int b = 0; b < 4; ++b) acc[a][b] = (float4v){0.f, 0.f, 0.f, 0.f};

    for (int j = 0; j < 16; ++j) {
        #pragma unroll
        for (int i = 0; i < 4; ++i) {
            async16(ag[i], As + lo_[i]);
            async16(bg[i], Bs + lo_[i]);
            ag[i] += 64; bg[i] += 64;
        }
        __syncthreads();

        short8 av[4][2], bv[4][2];
        #pragma unroll
        for (int mt = 0; mt < 4; ++mt) {
            av[mt][0] = *(const short8*)(As + aoff[mt][0]);
            av[mt][1] = *(const short8*)(As + aoff[mt][1]);
        }
        #pragma unroll
        for (int nt = 0; nt < 4; ++nt) {
            bv[nt][0] = *(const short8*)(Bs + boff[nt][0]);
            bv[nt][1] = *(const short8*)(Bs + boff[nt][1]);
        }
        #pragma unroll
        for (int kt = 0; kt < 2; ++kt)
            #pragma unroll
            for (int mt = 0; mt < 4; ++mt)
                #pragma unroll
                for (int nt = 0; nt < 4; ++nt)
                    acc[mt][nt] = __builtin_amdgcn_mfma_f32_16x16x32_bf16(
                        av[mt][kt], bv[nt][kt], acc[mt][nt], 0, 0, 0);
        __syncthreads();
    }

    #pragma unroll
    for (int nt = 0; nt < 4; ++nt) {
        int n = n0 + wn * 64 + nt * 16 + cc;
        float bias = bo[n];
        #pragma unroll
        for (int mt = 0; mt < 4; ++mt)
            #pragma unroll
            for (int rr = 0; rr < 4; ++rr) {
                int m = m0 + wm * 64 + mt * 16 + q * 4 + rr;
                out[(size_t)m * DMODEL + n] = acc[mt][nt][rr] + bias;
            }
    }
}

// ---------------------------------------------------------------------------
extern "C" void kernel_launch(void* const* d_in, const int* in_sizes, int n_in,
                              void* d_out, int out_size, void* d_ws, size_t ws_size,
                              hipStream_t stream)
{
    const float* x  = (const float*)d_in[0];
    const float* Wq = (const float*)d_in[1];
    const float* Wk = (const float*)d_in[2];
    const float* Wv = (const float*)d_in[3];
    const float* Wo = (const float*)d_in[4];
    const float* bo = (const float*)d_in[5];
    float* out = (float*)d_out;

    // ws (64MB): [0,16M) Qb (->Wob after attn)  [16,32) Kb  [32,48) Vt
    //            [48,64) WpT (first 6MB, dead after qkv) -> Ob (attn output)
    // Xb (bf16 X, 16MB) in d_out's first half (dead before oproj writes out).
    const size_t SEG = (size_t)8 * 1024 * 1024;
    ushort_t* Qb  = (ushort_t*)d_ws;
    ushort_t* Kb  = Qb + SEG;
    ushort_t* Vtb = Kb + SEG;
    ushort_t* WpT = Vtb + SEG;
    ushort_t* Ob  = WpT;         // WpT dead after qkv_gemm
    ushort_t* Xb  = (ushort_t*)d_out;
    ushort_t* Wob = Qb;          // Qb dead after attn

    cvt_f32_bf16<<<dim3(2048),    256, 0, stream>>>(x, Xb);
    pack_w      <<<dim3(16, 48),  256, 0, stream>>>(Wq, Wk, Wv, WpT);
    qkv_gemm    <<<dim3(384),     512, 0, stream>>>(Xb, WpT, Qb, Kb, Vtb);
    attn        <<<dim3(1024),    256, 0, stream>>>(Qb, Kb, Vtb, Ob);
    cvt_f32_bf16<<<dim3(256),     256, 0, stream>>>(Wo, Wob);
    oproj_gemm  <<<dim3(512),     256, 0, stream>>>(Ob, Wob, bo, out);
}

// Round 2
// 237.083 us; speedup vs baseline: 1.0709x; 1.0709x over previous
//
#include <hip/hip_runtime.h>
#include <hip/hip_bf16.h>

#define BBATCH 8
#define TSEQ   1024
#define DMODEL 1024
#define NHEAD  16
#define HSZ    64

typedef unsigned short ushort_t;
typedef __attribute__((ext_vector_type(8))) short short8;
typedef __attribute__((ext_vector_type(4))) float float4v;

__device__ __forceinline__ ushort_t f2bf(float f) {
    __hip_bfloat16 h = __float2bfloat16(f);
    return *reinterpret_cast<ushort_t*>(&h);
}
// fast fp32->bf16, round-half-up
__device__ __forceinline__ ushort_t f2bf_fast(float f) {
    return (ushort_t)((__float_as_uint(f) + 0x8000u) >> 16);
}
// pack two fp32 -> uint {bf16(lo), bf16(hi)}
__device__ __forceinline__ unsigned int pack_bf2(float lo, float hi) {
    unsigned int a = __float_as_uint(lo) + 0x8000u;
    unsigned int b = __float_as_uint(hi) + 0x8000u;
    return __builtin_amdgcn_perm(b, a, 0x07060302u);
}

__device__ __forceinline__ short8 cvt8(const float* f) {
    union { ushort_t u[8]; short8 v; } r;
    #pragma unroll
    for (int e = 0; e < 8; ++e) r.u[e] = f2bf(f[e]);
    return r.v;
}

// async global->LDS, 16B/lane; lds base wave-uniform (HW: base + lane*16)
__device__ __forceinline__ void async16(const ushort_t* g, ushort_t* l) {
    __builtin_amdgcn_global_load_lds(
        (const __attribute__((address_space(1))) unsigned int*)g,
        (__attribute__((address_space(3))) unsigned int*)l, 16, 0, 0);
}

template<int N> __device__ __forceinline__ void vwait() {
    if constexpr (N == 4)      asm volatile("s_waitcnt vmcnt(4)" ::: "memory");
    else if constexpr (N == 2) asm volatile("s_waitcnt vmcnt(2)" ::: "memory");
    else if constexpr (N == 0) asm volatile("s_waitcnt vmcnt(0)" ::: "memory");
    // N < 0: no wait
}

// ---------------------------------------------------------------------------
// cvt_f32_bf16: generic fp32 -> bf16, 16 elems/thread (X, Wo)
// ---------------------------------------------------------------------------
__global__ __launch_bounds__(256) void cvt_f32_bf16(
    const float* __restrict__ src, ushort_t* __restrict__ dst)
{
    const size_t idx = ((size_t)blockIdx.x * 256 + threadIdx.x) * 16;
    float f[16];
    *(float4*)(f + 0)  = *(const float4*)(src + idx);
    *(float4*)(f + 4)  = *(const float4*)(src + idx + 4);
    *(float4*)(f + 8)  = *(const float4*)(src + idx + 8);
    *(float4*)(f + 12) = *(const float4*)(src + idx + 12);
    uint4 o0 = make_uint4(pack_bf2(f[0], f[1]),   pack_bf2(f[2], f[3]),
                          pack_bf2(f[4], f[5]),   pack_bf2(f[6], f[7]));
    uint4 o1 = make_uint4(pack_bf2(f[8], f[9]),   pack_bf2(f[10], f[11]),
                          pack_bf2(f[12], f[13]), pack_bf2(f[14], f[15]));
    *(uint4*)(dst + idx) = o0;
    *(uint4*)(dst + idx + 8) = o1;
}

// ---------------------------------------------------------------------------
// pack_w: WpackT[w*1024 + h*64 + s][d] = W_w[h][d][s]  (fp32 -> bf16, n-major)
// ---------------------------------------------------------------------------
__global__ __launch_bounds__(256) void pack_w(
    const float* __restrict__ Wq, const float* __restrict__ Wk,
    const float* __restrict__ Wv, ushort_t* __restrict__ WpT)
{
    __shared__ ushort_t L[64 * 72];
    const int tid = threadIdx.x;
    const int d0 = blockIdx.x * 64;
    const int wh = blockIdx.y;
    const int w = wh >> 4, h = wh & 15;
    const float* W = (w == 0 ? Wq : (w == 1 ? Wk : Wv)) + (size_t)h * DMODEL * HSZ;

    int dr = tid >> 2, sc = (tid & 3) * 16;
    const float4* src = (const float4*)(W + (size_t)(d0 + dr) * HSZ + sc);
    float f[16];
    *(float4*)(f + 0) = src[0]; *(float4*)(f + 4) = src[1];
    *(float4*)(f + 8) = src[2]; *(float4*)(f + 12) = src[3];
    *(short8*)(L + dr * 72 + sc)     = cvt8(f);
    *(short8*)(L + dr * 72 + sc + 8) = cvt8(f + 8);
    __syncthreads();

    int s = tid >> 2, dc = (tid & 3) * 16;
    union { ushort_t u[16]; short8 v[2]; } o;
    #pragma unroll
    for (int j = 0; j < 16; ++j) o.u[j] = L[(dc + j) * 72 + s];
    ushort_t* dst = WpT + (size_t)(w * 1024 + h * 64 + s) * DMODEL + d0 + dc;
    *(short8*)dst = o.v[0];
    *(short8*)(dst + 8) = o.v[1];
}

// ---------------------------------------------------------------------------
// qkv_gemm: 256x256 tile, BK=64, 8 waves (2x4), double-buffered LDS.
// Faithful m201-style 4-phase/K-step schedule:
//   ph0: ds Alo(8)+Blo(4) | stage Alo(kt+1) | bar | MFMA Q00 | vmcnt(4) | bar
//   ph1: ds Ahi(8)        | stage Blo(kt+1) | bar | MFMA Q10 | vmcnt(4) | bar
//   ph2: ds Bhi(4)        | stage Ahi(kt+1) | bar | MFMA Q11 |           bar
//   ph3:                  | stage Bhi(kt+1) | bar | MFMA Q01 | vmcnt(4) | bar
// Staging: exactly 1 half-tile (2 global_load_lds/wave) per phase into
// buf[cur^1] (holds kt-1 data, fully dead). Periodic 2-loads/phase stream
// => vmcnt(4) == "everything issued >=2 phases ago landed", confirming
// precisely the half-tile the next phase reads. Invariant at K-step
// boundary: 4 outstanding = {Ahi,Bhi of kt+1}. Tail uses vmcnt(2)/(0).
// Grid 384 = 8 XCD * (32 QK + 16 V); per-XCD 4-m-tile band (2MB X).
// QK blocks: rows = s (weights in As) -> coalesced [t][s] stores.
// V blocks: rows = t (X in As) -> stores direct to Vt[s][t].
// ---------------------------------------------------------------------------
template<bool STG, int W0, int W1, int W3>
__device__ __forceinline__ void ktile_step(
    ushort_t* As, ushort_t* Bs,          // read buffers (kt)
    ushort_t* An, ushort_t* Bn,          // stage buffers (kt+1)
    const ushort_t* (&gA)[4], const ushort_t* (&gB)[4],
    const int wave,
    const int aoff0, const int aoff1, const int boff0, const int boff1,
    float4v (&acc)[8][4])
{
    short8 aLo[4][2], aHi[4][2], bLo[2][2], bHi[2][2];

    // ---- ph0: read Alo + Blo; stage Alo(kt+1); MFMA Q00 (a0-3 x b0-1)
    #pragma unroll
    for (int a = 0; a < 4; ++a) {
        aLo[a][0] = *(const short8*)(As + aoff0 + a * 1024);
        aLo[a][1] = *(const short8*)(As + aoff1 + a * 1024);
    }
    #pragma unroll
    for (int b = 0; b < 2; ++b) {
        bLo[b][0] = *(const short8*)(Bs + boff0 + b * 1024);
        bLo[b][1] = *(const short8*)(Bs + boff1 + b * 1024);
    }
    if (STG) {
        async16(gA[0], An + 0 * 4096 + wave * 512);
        async16(gA[1], An + 1 * 4096 + wave * 512);
    }
    __builtin_amdgcn_s_barrier();
    __builtin_amdgcn_s_setprio(1);
    #pragma unroll
    for (int k = 0; k < 2; ++k)
        #pragma unroll
        for (int a = 0; a < 4; ++a)
            #pragma unroll
            for (int b = 0; b < 2; ++b)
                acc[a][b] = __builtin_amdgcn_mfma_f32_16x16x32_bf16(
                    aLo[a][k], bLo[b][k], acc[a][b], 0, 0, 0);
    __builtin_amdgcn_s_setprio(0);
    vwait<W0>();
    __builtin_amdgcn_s_barrier();

    // ---- ph1: read Ahi; stage Blo(kt+1); MFMA Q10 (a4-7 x b0-1)
    #pragma unroll
    for (int a = 0; a < 4; ++a) {
        aHi[a][0] = *(const short8*)(As + aoff0 + (a + 4) * 1024);
        aHi[a][1] = *(const short8*)(As + aoff1 + (a + 4) * 1024);
    }
    if (STG) {
        async16(gB[0], Bn + 0 * 4096 + wave * 512);
        async16(gB[1], Bn + 1 * 4096 + wave * 512);
    }
    __builtin_amdgcn_s_barrier();
    __builtin_amdgcn_s_setprio(1);
    #pragma unroll
    for (int k = 0; k < 2; ++k)
        #pragma unroll
        for (int a = 0; a < 4; ++a)
            #pragma unroll
            for (int b = 0; b < 2; ++b)
                acc[a + 4][b] = __builtin_amdgcn_mfma_f32_16x16x32_bf16(
                    aHi[a][k], bLo[b][k], acc[a + 4][b], 0, 0, 0);
    __builtin_amdgcn_s_setprio(0);
    vwait<W1>();
    __builtin_amdgcn_s_barrier();

    // ---- ph2: read Bhi; stage Ahi(kt+1); MFMA Q11 (a4-7 x b2-3); no wait
    #pragma unroll
    for (int b = 0; b < 2; ++b) {
        bHi[b][0] = *(const short8*)(Bs + boff0 + (b + 2) * 1024);
        bHi[b][1] = *(const short8*)(Bs + boff1 + (b + 2) * 1024);
    }
    if (STG) {
        async16(gA[2], An + 2 * 4096 + wave * 512);
        async16(gA[3], An + 3 * 4096 + wave * 512);
    }
    __builtin_amdgcn_s_barrier();
    __builtin_amdgcn_s_setprio(1);
    #pragma unroll
    for (int k = 0; k < 2; ++k)
        #pragma unroll
        for (int a = 0; a < 4; ++a)
            #pragma unroll
            for (int b = 0; b < 2; ++b)
                acc[a + 4][b + 2] = __builtin_amdgcn_mfma_f32_16x16x32_bf16(
                    aHi[a][k], bHi[b][k], acc[a + 4][b + 2], 0, 0, 0);
    __builtin_amdgcn_s_setprio(0);
    __builtin_amdgcn_s_barrier();

    // ---- ph3: stage Bhi(kt+1); MFMA Q01 (a0-3 x b2-3, all regs)
    if (STG) {
        async16(gB[2], Bn + 2 * 4096 + wave * 512);
        async16(gB[3], Bn + 3 * 4096 + wave * 512);
        #pragma unroll
        for (int i = 0; i < 4; ++i) { gA[i] += 64; gB[i] += 64; }
    }
    __builtin_amdgcn_s_barrier();
    __builtin_amdgcn_s_setprio(1);
    #pragma unroll
    for (int k = 0; k < 2; ++k)
        #pragma unroll
        for (int a = 0; a < 4; ++a)
            #pragma unroll
            for (int b = 0; b < 2; ++b)
                acc[a][b + 2] = __builtin_amdgcn_mfma_f32_16x16x32_bf16(
                    aLo[a][k], bHi[b][k], acc[a][b + 2], 0, 0, 0);
    __builtin_amdgcn_s_setprio(0);
    vwait<W3>();
    __builtin_amdgcn_s_barrier();
}

__global__ __launch_bounds__(512, 2) void qkv_gemm(
    const ushort_t* __restrict__ Xb, const ushort_t* __restrict__ WpT,
    ushort_t* __restrict__ Qb, ushort_t* __restrict__ Kb, ushort_t* __restrict__ Vt)
{
    __shared__ ushort_t As0[256 * 64];
    __shared__ ushort_t Bs0[256 * 64];
    __shared__ ushort_t As1[256 * 64];
    __shared__ ushort_t Bs1[256 * 64];

    const int tid = threadIdx.x;
    const int wave = tid >> 6, lane = tid & 63;
    const int q = lane >> 4, cc = lane & 15;
    const int wm = wave >> 2, wn = wave & 3;

    // block -> tile: per-XCD 48 blocks = 32 QK (tn 0-7 x 4 m-tiles) + 16 V
    const int bid = blockIdx.x;
    const int xcd = bid & 7, lo = bid >> 3;
    const bool isV = (lo >= 32);
    int tn, tm;
    if (!isV) { tn = lo >> 2;        tm = xcd * 4 + (lo & 3); }
    else      { int v = lo - 32; tn = v >> 2; tm = xcd * 4 + (v & 3); }
    const int n0 = (isV ? 2048 : 0) + tn * 256;   // row range in WpT space
    const int m0 = tm * 256;                      // row range in Xb space

    // MFMA row operand (staged in As): weights for QK, X for V
    const ushort_t* pA = isV ? Xb + (size_t)m0 * DMODEL : WpT + (size_t)n0 * DMODEL;
    const ushort_t* pB = isV ? WpT + (size_t)n0 * DMODEL : Xb + (size_t)m0 * DMODEL;

    // staging addresses: instance i covers rows [i*64, i*64+64); XOR-8 source
    // swizzle so linear LDS dest holds LDS[row][g] = glob[row][g ^ (row&7)]
    const int srow = lane >> 3;
    const int chx = (lane & 7) ^ srow;
    const ushort_t* gA[4]; const ushort_t* gB[4];
    #pragma unroll
    for (int i = 0; i < 4; ++i) {
        int row = i * 64 + wave * 8 + srow;
        gA[i] = pA + (size_t)row * DMODEL + chx * 8;
        gB[i] = pB + (size_t)row * DMODEL + chx * 8;
    }

    // ds_read offsets (elements); row&7 == cc&7 for all fragments
    const int c7 = cc & 7;
    const int arow = wm * 128 + cc;
    const int brow = wn * 64 + cc;
    const int aoff0 = arow * 64 + ((q ^ c7) * 8);
    const int aoff1 = arow * 64 + (((4 + q) ^ c7) * 8);
    const int boff0 = brow * 64 + ((q ^ c7) * 8);
    const int boff1 = brow * 64 + (((4 + q) ^ c7) * 8);

    float4v acc[8][4];
    #pragma unroll
    for (int a = 0; a < 8; ++a)
        #pragma unroll
        for (int b = 0; b < 4; ++b) acc[a][b] = (float4v){0.f, 0.f, 0.f, 0.f};

    // prologue: stage kt0 -> buf0 fully, drain once, barrier
    async16(gA[0], As0 + 0 * 4096 + wave * 512);
    async16(gA[1], As0 + 1 * 4096 + wave * 512);
    async16(gB[0], Bs0 + 0 * 4096 + wave * 512);
    async16(gB[1], Bs0 + 1 * 4096 + wave * 512);
    async16(gA[2], As0 + 2 * 4096 + wave * 512);
    async16(gA[3], As0 + 3 * 4096 + wave * 512);
    async16(gB[2], Bs0 + 2 * 4096 + wave * 512);
    async16(gB[3], Bs0 + 3 * 4096 + wave * 512);
    #pragma unroll
    for (int i = 0; i < 4; ++i) { gA[i] += 64; gB[i] += 64; }
    asm volatile("s_waitcnt vmcnt(0)" ::: "memory");
    __builtin_amdgcn_s_barrier();

    // 16 K-steps: kt0..13 in loop, kt14 stages kt15, kt15 tail
    #pragma unroll 1
    for (int it = 0; it < 7; ++it) {
        ktile_step<true, 4, 4, 4>(As0, Bs0, As1, Bs1, gA, gB, wave,
                                  aoff0, aoff1, boff0, boff1, acc);
        ktile_step<true, 4, 4, 4>(As1, Bs1, As0, Bs0, gA, gB, wave,
                                  aoff0, aoff1, boff0, boff1, acc);
    }
    ktile_step<true, 4, 4, 4>(As0, Bs0, As1, Bs1, gA, gB, wave,
                              aoff0, aoff1, boff0, boff1, acc);
    ktile_step<false, 2, 0, -1>(As1, Bs1, As0, Bs0, gA, gB, wave,
                                aoff0, aoff1, boff0, boff1, acc);

    // epilogue: inner loop walks the contiguous dim of each 128B line
    if (!isV) {
        ushort_t* Out = (n0 < 1024) ? Qb : Kb;
        const float osc = (n0 < 1024) ? 0.18033688011112042f : 1.0f;
        #pragma unroll
        for (int b = 0; b < 4; ++b) {
            int mc = m0 + wn * 64 + b * 16 + cc;         // t (col)
            int bb = mc >> 10, t = mc & 1023;
            #pragma unroll
            for (int a = 0; a < 8; ++a) {
                int nr = n0 + wm * 128 + a * 16 + q * 4; // s (row)
                int h = (nr >> 6) & 15, s0 = nr & 63;
                size_t addr = (((size_t)(bb * NHEAD + h)) * TSEQ + t) * HSZ + s0;
                uint2 pk = make_uint2(
                    pack_bf2(acc[a][b][0] * osc, acc[a][b][1] * osc),
                    pack_bf2(acc[a][b][2] * osc, acc[a][b][3] * osc));
                *(uint2*)(Out + addr) = pk;
            }
        }
    } else {
        #pragma unroll
        for (int b = 0; b < 4; ++b) {
            int nc = n0 + wn * 64 + b * 16 + cc;         // s (col)
            int h = (nc >> 6) & 15, s = nc & 63;
            #pragma unroll
            for (int a = 0; a < 8; ++a) {
                int mr = m0 + wm * 128 + a * 16 + q * 4; // t (row)
                int bb = mr >> 10, t0 = mr & 1023;
                size_t addr = (((size_t)(bb * NHEAD + h)) * HSZ + s) * TSEQ + t0;
                uint2 pk = make_uint2(pack_bf2(acc[a][b][0], acc[a][b][1]),
                                      pack_bf2(acc[a][b][2], acc[a][b][3]));
                *(uint2*)(Vt + addr) = pk;
            }
        }
    }
}

// ---------------------------------------------------------------------------
// attn: flash attention, Q-tile 128, KV-tile 64, dbuf DMA prefetch, exp2
// softmax without running max; causal mask only on the 2 diagonal jt-tiles
// (wave-uniform branch). 1-D grid 1024, bid&7 == bh&7 -> per-bh KV co-XCD.
// ---------------------------------------------------------------------------
__global__ __launch_bounds__(256) void attn(
    const ushort_t* __restrict__ Qb, const ushort_t* __restrict__ Kb,
    const ushort_t* __restrict__ Vt, ushort_t* __restrict__ Ob)
{
    __shared__ ushort_t Ks[2][64 * 64];
    __shared__ ushort_t VTs[2][64 * 64];
    __shared__ ushort_t Ps[4][32 * 72];
    const int tid = threadIdx.x;
    const int wave = tid >> 6, lane = tid & 63;
    const int q = lane >> 4, cc = lane & 15;
    const int bid = blockIdx.x;
    const int qt = 7 - (bid >> 7);    // big-J blocks first
    const int bh = bid & 127;
    const size_t base = (size_t)bh * TSEQ * HSZ;
    const int J = 2 * qt + 2;

    const ushort_t* kg[2]; const ushort_t* vg[2]; int dmo[2];
    #pragma unroll
    for (int i = 0; i < 2; ++i) {
        int rr = wave * 16 + i * 8 + (lane >> 3);
        int ch = (lane & 7) ^ (rr & 7);
        kg[i] = Kb + base + (size_t)rr * HSZ + ch * 8;
        vg[i] = Vt + base + (size_t)rr * TSEQ + ch * 8;
        dmo[i] = (wave * 16 + i * 8) * 64;
    }

    short8 qf[2][2];
    #pragma unroll
    for (int tt = 0; tt < 2; ++tt) {
        const ushort_t* qp = Qb + base +
            (size_t)(qt * 128 + wave * 32 + tt * 16 + cc) * HSZ + q * 8;
        qf[tt][0] = *(const short8*)qp;
        qf[tt][1] = *(const short8*)(qp + 32);
    }

    int koff[4][2], poff[2][2];
    #pragma unroll
    for (int ut = 0; ut < 4; ++ut)
        #pragma unroll
        for (int kt = 0; kt < 2; ++kt)
            koff[ut][kt] = (ut * 16 + cc) * 64 + (((kt * 4 + q) ^ (cc & 7)) * 8);
    #pragma unroll
    for (int tt = 0; tt < 2; ++tt)
        #pragma unroll
        for (int kt = 0; kt < 2; ++kt)
            poff[tt][kt] = (tt * 16 + cc) * 72 + kt * 32 + q * 8;

    float4v oacc[2][4];
    #pragma unroll
    for (int tt = 0; tt < 2; ++tt)
        #pragma unroll
        for (int st = 0; st < 4; ++st) oacc[tt][st] = (float4v){0.f, 0.f, 0.f, 0.f};
    float lsum[2] = {0.f, 0.f};

    #pragma unroll
    for (int i = 0; i < 2; ++i) {
        async16(kg[i], &Ks[0][dmo[i]]);
        async16(vg[i], &VTs[0][dmo[i]]);
    }
    __syncthreads();

    for (int jt = 0; jt < J; ++jt) {
        const ushort_t* Kc = Ks[jt & 1];
        const ushort_t* Vc = VTs[jt & 1];
        if (jt + 1 < J) {
            int nb = (jt + 1) & 1;
            #pragma unroll
            for (int i = 0; i < 2; ++i) {
                async16(kg[i] + (size_t)(jt + 1) * 64 * HSZ, &Ks[nb][dmo[i]]);
                async16(vg[i] + (jt + 1) * 64, &VTs[nb][dmo[i]]);
            }
        }

        float4v sc[4][2];
        #pragma unroll
        for (int ut = 0; ut < 4; ++ut)
            #pragma unroll
            for (int tt = 0; tt < 2; ++tt) sc[ut][tt] = (float4v){0.f, 0.f, 0.f, 0.f};
        #pragma unroll
        for (int kt = 0; kt < 2; ++kt) {
            short8 kf[4];
            #pragma unroll
            for (int ut = 0; ut < 4; ++ut) kf[ut] = *(const short8*)(Kc + koff[ut][kt]);
            #pragma unroll
            for (int ut = 0; ut < 4; ++ut) {
                sc[ut][0] = __builtin_amdgcn_mfma_f32_16x16x32_bf16(
                    kf[ut], qf[0][kt], sc[ut][0], 0, 0, 0);
                sc[ut][1] = __builtin_amdgcn_mfma_f32_16x16x32_bf16(
                    kf[ut], qf[1][kt], sc[ut][1], 0, 0, 0);
            }
        }

        if ((jt >> 1) == qt) {   // diagonal tiles: masked path
            #pragma unroll
            for (int tt = 0; tt < 2; ++tt) {
                const int tg = qt * 128 + wave * 32 + tt * 16 + cc;
                #pragma unroll
                for (int ut = 0; ut < 4; ++ut) {
                    float pv[4]; float ps = 0.f;
                    #pragma unroll
                    for (int rr = 0; rr < 4; ++rr) {
                        float p = exp2f(sc[ut][tt][rr]);
                        if ((jt * 64 + ut * 16 + q * 4 + rr) > tg) p = 0.f;
                        pv[rr] = p; ps += p;
                    }
                    lsum[tt] += ps;
                    *(uint2*)&Ps[wave][(tt * 16 + cc) * 72 + ut * 16 + q * 4] =
                        make_uint2(pack_bf2(pv[0], pv[1]), pack_bf2(pv[2], pv[3]));
                }
            }
        } else {                 // interior tiles: no mask
            #pragma unroll
            for (int tt = 0; tt < 2; ++tt) {
                #pragma unroll
                for (int ut = 0; ut < 4; ++ut) {
                    float pv[4]; float ps = 0.f;
                    #pragma unroll
                    for (int rr = 0; rr < 4; ++rr) {
                        float p = exp2f(sc[ut][tt][rr]);
                        pv[rr] = p; ps += p;
                    }
                    lsum[tt] += ps;
                    *(uint2*)&Ps[wave][(tt * 16 + cc) * 72 + ut * 16 + q * 4] =
                        make_uint2(pack_bf2(pv[0], pv[1]), pack_bf2(pv[2], pv[3]));
                }
            }
        }

        #pragma unroll
        for (int kt = 0; kt < 2; ++kt) {
            short8 pa0 = *(const short8*)&Ps[wave][poff[0][kt]];
            short8 pa1 = *(const short8*)&Ps[wave][poff[1][kt]];
            #pragma unroll
            for (int st = 0; st < 4; ++st) {
                short8 vf = *(const short8*)(Vc + koff[st][kt]);
                oacc[0][st] = __builtin_amdgcn_mfma_f32_16x16x32_bf16(
                    pa0, vf, oacc[0][st], 0, 0, 0);
                oacc[1][st] = __builtin_amdgcn_mfma_f32_16x16x32_bf16(
                    pa1, vf, oacc[1][st], 0, 0, 0);
            }
        }
        __syncthreads();
    }

    float inv[2];
    #pragma unroll
    for (int tt = 0; tt < 2; ++tt) {
        float l = lsum[tt];
        l += __shfl_xor(l, 16);
        l += __shfl_xor(l, 32);
        inv[tt] = 1.f / l;
    }
    const int b = bh >> 4, h = bh & 15;
    #pragma unroll
    for (int tt = 0; tt < 2; ++tt)
        #pragma unroll
        for (int rr = 0; rr < 4; ++rr) {
            float iv = __shfl(inv[tt], q * 4 + rr);
            int t = qt * 128 + wave * 32 + tt * 16 + q * 4 + rr;
            size_t rb = ((size_t)b * TSEQ + t) * DMODEL + h * HSZ;
            #pragma unroll
            for (int st = 0; st < 4; ++st)
                Ob[rb + st * 16 + cc] = f2bf_fast(oacc[tt][st][rr] * iv);
        }
}

// ---------------------------------------------------------------------------
// oproj_gemm: out[m][n] = sum_k Ob[m][k]*Wob[n][k] + bo[n]. m97 structure.
// XCD m-banding: per-XCD 8 m-blocks (2 MB Ob) + Wob 2 MB -> 4 MB, L2-resident.
// grid 512.
// ---------------------------------------------------------------------------
__global__ __launch_bounds__(256) void oproj_gemm(
    const ushort_t* __restrict__ Obuf, const ushort_t* __restrict__ Wob,
    const float* __restrict__ bo, float* __restrict__ out)
{
    __shared__ ushort_t As[128 * 64];
    __shared__ ushort_t Bs[128 * 64];
    const int tid = threadIdx.x;
    const int wave = tid >> 6, lane = tid & 63;
    const int q = lane >> 4, cc = lane & 15;
    const int bid = blockIdx.x;
    const int xcd = bid & 7, local = bid >> 3;
    const int n0 = (local >> 3) * 128;
    const int m0 = (xcd * 8 + (local & 7)) * 128;
    const int wm = wave >> 1, wn = wave & 1;

    const ushort_t* ag[4]; const ushort_t* bg[4]; int lo_[4];
    #pragma unroll
    for (int i = 0; i < 4; ++i) {
        int row = wave * 32 + i * 8 + (lane >> 3);
        int ch = (lane & 7) ^ (row & 7);
        ag[i] = Obuf + (size_t)(m0 + row) * DMODEL + ch * 8;
        bg[i] = Wob + (size_t)(n0 + row) * DMODEL + ch * 8;
        lo_[i] = (wave * 32 + i * 8) * 64;
    }
    int aoff[4][2], boff[4][2];
    #pragma unroll
    for (int mt = 0; mt < 4; ++mt) {
        int row = wm * 64 + mt * 16 + cc;
        #pragma unroll
        for (int kt = 0; kt < 2; ++kt)
            aoff[mt][kt] = row * 64 + (((kt * 4 + q) ^ (row & 7)) * 8);
    }
    #pragma unroll
    for (int nt = 0; nt < 4; ++nt) {
        int row = wn * 64 + nt * 16 + cc;
        #pragma unroll
        for (int kt = 0; kt < 2; ++kt)
            boff[nt][kt] = row * 64 + (((kt * 4 + q) ^ (row & 7)) * 8);
    }

    float4v acc[4][4];
    #pragma unroll
    for (int a = 0; a < 4; ++a)
        #pragma unroll
        for (int b = 0; b < 4; ++b) acc[a][b] = (float4v){0.f, 0.f, 0.f, 0.f};

    for (int j = 0; j < 16; ++j) {
        #pragma unroll
        for (int i = 0; i < 4; ++i) {
            async16(ag[i], As + lo_[i]);
            async16(bg[i], Bs + lo_[i]);
            ag[i] += 64; bg[i] += 64;
        }
        __syncthreads();

        short8 av[4][2], bv[4][2];
        #pragma unroll
        for (int mt = 0; mt < 4; ++mt) {
            av[mt][0] = *(const short8*)(As + aoff[mt][0]);
            av[mt][1] = *(const short8*)(As + aoff[mt][1]);
        }
        #pragma unroll
        for (int nt = 0; nt < 4; ++nt) {
            bv[nt][0] = *(const short8*)(Bs + boff[nt][0]);
            bv[nt][1] = *(const short8*)(Bs + boff[nt][1]);
        }
        #pragma unroll
        for (int kt = 0; kt < 2; ++kt)
            #pragma unroll
            for (int mt = 0; mt < 4; ++mt)
                #pragma unroll
                for (int nt = 0; nt < 4; ++nt)
                    acc[mt][nt] = __builtin_amdgcn_mfma_f32_16x16x32_bf16(
                        av[mt][kt], bv[nt][kt], acc[mt][nt], 0, 0, 0);
        __syncthreads();
    }

    #pragma unroll
    for (int nt = 0; nt < 4; ++nt) {
        int n = n0 + wn * 64 + nt * 16 + cc;
        float bias = bo[n];
        #pragma unroll
        for (int mt = 0; mt < 4; ++mt)
            #pragma unroll
            for (int rr = 0; rr < 4; ++rr) {
                int m = m0 + wm * 64 + mt * 16 + q * 4 + rr;
                out[(size_t)m * DMODEL + n] = acc[mt][nt][rr] + bias;
            }
    }
}

// ---------------------------------------------------------------------------
extern "C" void kernel_launch(void* const* d_in, const int* in_sizes, int n_in,
                              void* d_out, int out_size, void* d_ws, size_t ws_size,
                              hipStream_t stream)
{
    const float* x  = (const float*)d_in[0];
    const float* Wq = (const float*)d_in[1];
    const float* Wk = (const float*)d_in[2];
    const float* Wv = (const float*)d_in[3];
    const float* Wo = (const float*)d_in[4];
    const float* bo = (const float*)d_in[5];
    float* out = (float*)d_out;

    // ws (64MB): [0,16M) Qb (->Wob after attn)  [16,32) Kb  [32,48) Vt
    //            [48,64) WpT (first 6MB, dead after qkv) -> Ob (attn output)
    // Xb (bf16 X, 16MB) in d_out's first half (dead before oproj writes out).
    const size_t SEG = (size_t)8 * 1024 * 1024;
    ushort_t* Qb  = (ushort_t*)d_ws;
    ushort_t* Kb  = Qb + SEG;
    ushort_t* Vtb = Kb + SEG;
    ushort_t* WpT = Vtb + SEG;
    ushort_t* Ob  = WpT;         // WpT dead after qkv_gemm
    ushort_t* Xb  = (ushort_t*)d_out;
    ushort_t* Wob = Qb;          // Qb dead after attn

    cvt_f32_bf16<<<dim3(2048),    256, 0, stream>>>(x, Xb);
    pack_w      <<<dim3(16, 48),  256, 0, stream>>>(Wq, Wk, Wv, WpT);
    qkv_gemm    <<<dim3(384),     512, 0, stream>>>(Xb, WpT, Qb, Kb, Vtb);
    attn        <<<dim3(1024),    256, 0, stream>>>(Qb, Kb, Vtb, Ob);
    cvt_f32_bf16<<<dim3(256),     256, 0, stream>>>(Wo, Wob);
    oproj_gemm  <<<dim3(512),     256, 0, stream>>>(Ob, Wob, bo, out);
}

// Round 3
// 231.189 us; speedup vs baseline: 1.0982x; 1.0255x over previous
//
#include <hip/hip_runtime.h>
#include <hip/hip_bf16.h>

#define BBATCH 8
#define TSEQ   1024
#define DMODEL 1024
#define NHEAD  16
#define HSZ    64

typedef unsigned short ushort_t;
typedef __attribute__((ext_vector_type(8))) short short8;
typedef __attribute__((ext_vector_type(4))) float float4v;

__device__ __forceinline__ ushort_t f2bf(float f) {
    __hip_bfloat16 h = __float2bfloat16(f);
    return *reinterpret_cast<ushort_t*>(&h);
}
// fast fp32->bf16, round-half-up
__device__ __forceinline__ ushort_t f2bf_fast(float f) {
    return (ushort_t)((__float_as_uint(f) + 0x8000u) >> 16);
}
// pack two fp32 -> uint {bf16(lo), bf16(hi)}
__device__ __forceinline__ unsigned int pack_bf2(float lo, float hi) {
    unsigned int a = __float_as_uint(lo) + 0x8000u;
    unsigned int b = __float_as_uint(hi) + 0x8000u;
    return __builtin_amdgcn_perm(b, a, 0x07060302u);
}

__device__ __forceinline__ short8 cvt8(const float* f) {
    union { ushort_t u[8]; short8 v; } r;
    #pragma unroll
    for (int e = 0; e < 8; ++e) r.u[e] = f2bf(f[e]);
    return r.v;
}

// async global->LDS, 16B/lane; lds base wave-uniform (HW: base + lane*16)
__device__ __forceinline__ void async16(const ushort_t* g, ushort_t* l) {
    __builtin_amdgcn_global_load_lds(
        (const __attribute__((address_space(1))) unsigned int*)g,
        (__attribute__((address_space(3))) unsigned int*)l, 16, 0, 0);
}

template<int N> __device__ __forceinline__ void vwait() {
    if constexpr (N == 3)      asm volatile("s_waitcnt vmcnt(3)" ::: "memory");
    else if constexpr (N == 0) asm volatile("s_waitcnt vmcnt(0)" ::: "memory");
    // N < 0: no wait
}

// ---------------------------------------------------------------------------
// cvt_f32_bf16: generic fp32 -> bf16, 16 elems/thread (X, Wo)
// ---------------------------------------------------------------------------
__global__ __launch_bounds__(256) void cvt_f32_bf16(
    const float* __restrict__ src, ushort_t* __restrict__ dst)
{
    const size_t idx = ((size_t)blockIdx.x * 256 + threadIdx.x) * 16;
    float f[16];
    *(float4*)(f + 0)  = *(const float4*)(src + idx);
    *(float4*)(f + 4)  = *(const float4*)(src + idx + 4);
    *(float4*)(f + 8)  = *(const float4*)(src + idx + 8);
    *(float4*)(f + 12) = *(const float4*)(src + idx + 12);
    uint4 o0 = make_uint4(pack_bf2(f[0], f[1]),   pack_bf2(f[2], f[3]),
                          pack_bf2(f[4], f[5]),   pack_bf2(f[6], f[7]));
    uint4 o1 = make_uint4(pack_bf2(f[8], f[9]),   pack_bf2(f[10], f[11]),
                          pack_bf2(f[12], f[13]), pack_bf2(f[14], f[15]));
    *(uint4*)(dst + idx) = o0;
    *(uint4*)(dst + idx + 8) = o1;
}

// ---------------------------------------------------------------------------
// pack_w: WpackT[w*1024 + h*64 + s][d] = W_w[h][d][s]  (fp32 -> bf16, n-major)
// ---------------------------------------------------------------------------
__global__ __launch_bounds__(256) void pack_w(
    const float* __restrict__ Wq, const float* __restrict__ Wk,
    const float* __restrict__ Wv, ushort_t* __restrict__ WpT)
{
    __shared__ ushort_t L[64 * 72];
    const int tid = threadIdx.x;
    const int d0 = blockIdx.x * 64;
    const int wh = blockIdx.y;
    const int w = wh >> 4, h = wh & 15;
    const float* W = (w == 0 ? Wq : (w == 1 ? Wk : Wv)) + (size_t)h * DMODEL * HSZ;

    int dr = tid >> 2, sc = (tid & 3) * 16;
    const float4* src = (const float4*)(W + (size_t)(d0 + dr) * HSZ + sc);
    float f[16];
    *(float4*)(f + 0) = src[0]; *(float4*)(f + 4) = src[1];
    *(float4*)(f + 8) = src[2]; *(float4*)(f + 12) = src[3];
    *(short8*)(L + dr * 72 + sc)     = cvt8(f);
    *(short8*)(L + dr * 72 + sc + 8) = cvt8(f + 8);
    __syncthreads();

    int s = tid >> 2, dc = (tid & 3) * 16;
    union { ushort_t u[16]; short8 v[2]; } o;
    #pragma unroll
    for (int j = 0; j < 16; ++j) o.u[j] = L[(dc + j) * 72 + s];
    ushort_t* dst = WpT + (size_t)(w * 1024 + h * 64 + s) * DMODEL + d0 + dc;
    *(short8*)dst = o.v[0];
    *(short8*)(dst + 8) = o.v[1];
}

// ---------------------------------------------------------------------------
// qkv_gemm: uniform 128(A-rows) x 256(B-rows) tiles, BK=32, 8 waves (2x4),
// TRIPLE-buffered LDS (72KB), ONE barrier per K-step, counted vmcnt(3).
//
// Per K-step t (identical every step):
//   8x ds_read_b128 (a0-3, b0-3 from buf[t%3])
//   3x global_load_lds -> buf[(t+2)%3]   (A:1 instr, B:2 instrs per wave)
//   setprio(1); 16 independent MFMA; setprio(0)
//   s_waitcnt vmcnt(3)    // confirms buf[(t+1)%3] fully landed (t-1's loads)
//   s_barrier             // single barrier: bounds wave skew to 1 step
// Safety: stage target buf[(t+2)%3] was read during t-1; those reads
// completed before each wave's t-1 MFMA (lgkmcnt), which precedes the
// end-of-(t-1) barrier -> no read-write race with one barrier.
//
// Grid 768 = 512 QK + 256 V, all blocks identical 67-MFLOP work -> exactly
// 3 full dispatch rounds on 256 CUs (no tail). Per-XCD working set 4MB
// (2MB X band + 2MB W panels) = L2-fit.
// QK: A = W rows (s-dim), B = X rows (t-dim) -> out[s][t] -> Qb/Kb[bh][t][s].
// V:  A = X rows (t-dim), B = Wv rows (s-dim) -> out[t][s] -> Vt[bh][s][t].
// Q pre-scaled by 0.125*log2(e).
// ---------------------------------------------------------------------------
template<bool STG, int VW>
__device__ __forceinline__ void kstep32(
    const ushort_t* Ab, const ushort_t* Bb,     // read buffers (step t)
    ushort_t* An, ushort_t* Bn,                 // stage buffers (step t+2)
    const ushort_t*& gA, const ushort_t*& gB,   // advance +32 when STG
    const int wave,
    const int (&aoff)[4], const int (&boff)[4],
    float4v (&acc)[4][4])
{
    short8 av[4], bv[4];
    #pragma unroll
    for (int a = 0; a < 4; ++a) av[a] = *(const short8*)(Ab + aoff[a]);
    #pragma unroll
    for (int b = 0; b < 4; ++b) bv[b] = *(const short8*)(Bb + boff[b]);
    if (STG) {
        async16(gA,                  An + wave * 512);
        async16(gB,                  Bn + wave * 512);
        async16(gB + 128 * DMODEL,   Bn + 4096 + wave * 512);
        gA += 32; gB += 32;
    }
    __builtin_amdgcn_s_setprio(1);
    #pragma unroll
    for (int a = 0; a < 4; ++a)
        #pragma unroll
        for (int b = 0; b < 4; ++b)
            acc[a][b] = __builtin_amdgcn_mfma_f32_16x16x32_bf16(
                av[a], bv[b], acc[a][b], 0, 0, 0);
    __builtin_amdgcn_s_setprio(0);
    vwait<VW>();
    __builtin_amdgcn_s_barrier();
}

__global__ __launch_bounds__(512, 2) void qkv_gemm(
    const ushort_t* __restrict__ Xb, const ushort_t* __restrict__ WpT,
    ushort_t* __restrict__ Qb, ushort_t* __restrict__ Kb, ushort_t* __restrict__ Vt)
{
    __shared__ ushort_t Ab[3][128 * 32];   // 3 x 8KB
    __shared__ ushort_t Bb[3][256 * 32];   // 3 x 16KB  -> 72KB total

    const int tid = threadIdx.x;
    const int wave = tid >> 6, lane = tid & 63;
    const int q = lane >> 4, cc = lane & 15;
    const int wm = wave >> 2, wn = wave & 3;   // wave grid 2(A) x 4(B)

    // block -> tile. QK: bid 0..511; V: bid 512..767. xcd = bid & 7.
    const int bid = blockIdx.x;
    const int xcd = bid & 7;
    const bool isV = (bid >= 512);
    int ta, tb;    // A-tile (128 rows), B-tile (256 rows)
    if (!isV) {
        int lo = bid >> 3;            // 0..63
        ta = lo >> 2;                 // W n-tile 0..15 (tn<8: Q, else K)
        tb = xcd * 4 + (lo & 3);      // X m-tile 0..31 (XCD band: 2MB)
    } else {
        int lo = (bid - 512) >> 3;    // 0..31
        ta = xcd * 8 + (lo & 7);      // X m-tile 0..63 (XCD band: 2MB)
        tb = lo >> 3;                 // Wv n-tile 0..3
    }
    const ushort_t* pA = isV ? Xb  + (size_t)ta * 128 * DMODEL
                             : WpT + (size_t)ta * 128 * DMODEL;
    const ushort_t* pB = isV ? WpT + (size_t)(2048 + tb * 256) * DMODEL
                             : Xb  + (size_t)tb * 256 * DMODEL;

    // staging source addrs: per instr, wave covers 16 rows; XOR-4 source
    // swizzle so linear LDS holds LDS[r][c] = glob[r][c ^ (r&3)] (c,r chunks)
    const int srow = lane >> 2;                      // 0..15 row-in-wave
    const int chx = (lane & 3) ^ (srow & 3);         // swizzled 8-elem chunk
    const ushort_t* gA = pA + (size_t)(wave * 16 + srow) * DMODEL + chx * 8;
    const ushort_t* gB = pB + (size_t)(wave * 16 + srow) * DMODEL + chx * 8;
    // (B instance 1 = gB + 128*DMODEL, handled in kstep32)

    // ds_read offsets (elems): frag f at row = w*64 + f*16 + cc, k-chunk q
    int aoff[4], boff[4];
    #pragma unroll
    for (int f = 0; f < 4; ++f) {
        aoff[f] = (wm * 64 + f * 16 + cc) * 32 + ((q ^ (cc & 3)) * 8);
        boff[f] = (wn * 64 + f * 16 + cc) * 32 + ((q ^ (cc & 3)) * 8);
    }

    float4v acc[4][4];
    #pragma unroll
    for (int a = 0; a < 4; ++a)
        #pragma unroll
        for (int b = 0; b < 4; ++b) acc[a][b] = (float4v){0.f, 0.f, 0.f, 0.f};

    // prologue: stage t0 -> buf0, t1 -> buf1; confirm t0; barrier
    async16(gA,                Ab[0] + wave * 512);
    async16(gB,                Bb[0] + wave * 512);
    async16(gB + 128 * DMODEL, Bb[0] + 4096 + wave * 512);
    gA += 32; gB += 32;
    async16(gA,                Ab[1] + wave * 512);
    async16(gB,                Bb[1] + wave * 512);
    async16(gB + 128 * DMODEL, Bb[1] + 4096 + wave * 512);
    gA += 32; gB += 32;
    vwait<3>();
    __builtin_amdgcn_s_barrier();

    // 32 K-steps: 30 steady (stage t+2, vmcnt(3)), then t30 (vmcnt 0), t31
    #pragma unroll 1
    for (int it = 0; it < 10; ++it) {
        kstep32<true, 3>(Ab[0], Bb[0], Ab[2], Bb[2], gA, gB, wave, aoff, boff, acc);
        kstep32<true, 3>(Ab[1], Bb[1], Ab[0], Bb[0], gA, gB, wave, aoff, boff, acc);
        kstep32<true, 3>(Ab[2], Bb[2], Ab[1], Bb[1], gA, gB, wave, aoff, boff, acc);
    }
    kstep32<false, 0>(Ab[0], Bb[0], Ab[2], Bb[2], gA, gB, wave, aoff, boff, acc);
    kstep32<false, -1>(Ab[1], Bb[1], Ab[0], Bb[0], gA, gB, wave, aoff, boff, acc);

    // epilogue: out[rowA = ta*128 + wm*64 + a*16 + q*4+rr]
    //              [colB = tb-range + wn*64 + b*16 + cc]
    // inner loop a -> 4x8B stores land in one 128B line
    if (!isV) {
        ushort_t* Out = (ta < 8) ? Qb : Kb;
        const float osc = (ta < 8) ? 0.18033688011112042f : 1.0f;
        const int h = ((ta * 128 + wm * 64) >> 6) & 15;   // head (uniform/wave)
        #pragma unroll
        for (int b = 0; b < 4; ++b) {
            int mc = tb * 256 + wn * 64 + b * 16 + cc;    // t (col)
            int bb = mc >> 10, t = mc & 1023;
            size_t rb = (((size_t)(bb * NHEAD + h)) * TSEQ + t) * HSZ;
            #pragma unroll
            for (int a = 0; a < 4; ++a) {
                int s0 = a * 16 + q * 4;                  // s within head
                uint2 pk = make_uint2(
                    pack_bf2(acc[a][b][0] * osc, acc[a][b][1] * osc),
                    pack_bf2(acc[a][b][2] * osc, acc[a][b][3] * osc));
                *(uint2*)(Out + rb + s0) = pk;
            }
        }
    } else {
        #pragma unroll
        for (int b = 0; b < 4; ++b) {
            int nc = tb * 256 + wn * 64 + b * 16 + cc;    // s (col), 0..1023
            int h = nc >> 6, s = nc & 63;
            #pragma unroll
            for (int a = 0; a < 4; ++a) {
                int mr = ta * 128 + wm * 64 + a * 16 + q * 4;  // t (row)
                int bb = mr >> 10, t0 = mr & 1023;
                size_t addr = (((size_t)(bb * NHEAD + h)) * HSZ + s) * TSEQ + t0;
                uint2 pk = make_uint2(pack_bf2(acc[a][b][0], acc[a][b][1]),
                                      pack_bf2(acc[a][b][2], acc[a][b][3]));
                *(uint2*)(Vt + addr) = pk;
            }
        }
    }
}

// ---------------------------------------------------------------------------
// attn: flash attention, Q-tile 128, KV-tile 64, dbuf DMA prefetch, exp2
// softmax without running max; causal mask only on the 2 diagonal jt-tiles
// (wave-uniform branch). 1-D grid 1024, bid&7 == bh&7 -> per-bh KV co-XCD.
// ---------------------------------------------------------------------------
__global__ __launch_bounds__(256) void attn(
    const ushort_t* __restrict__ Qb, const ushort_t* __restrict__ Kb,
    const ushort_t* __restrict__ Vt, ushort_t* __restrict__ Ob)
{
    __shared__ ushort_t Ks[2][64 * 64];
    __shared__ ushort_t VTs[2][64 * 64];
    __shared__ ushort_t Ps[4][32 * 72];
    const int tid = threadIdx.x;
    const int wave = tid >> 6, lane = tid & 63;
    const int q = lane >> 4, cc = lane & 15;
    const int bid = blockIdx.x;
    const int qt = 7 - (bid >> 7);    // big-J blocks first
    const int bh = bid & 127;
    const size_t base = (size_t)bh * TSEQ * HSZ;
    const int J = 2 * qt + 2;

    const ushort_t* kg[2]; const ushort_t* vg[2]; int dmo[2];
    #pragma unroll
    for (int i = 0; i < 2; ++i) {
        int rr = wave * 16 + i * 8 + (lane >> 3);
        int ch = (lane & 7) ^ (rr & 7);
        kg[i] = Kb + base + (size_t)rr * HSZ + ch * 8;
        vg[i] = Vt + base + (size_t)rr * TSEQ + ch * 8;
        dmo[i] = (wave * 16 + i * 8) * 64;
    }

    short8 qf[2][2];
    #pragma unroll
    for (int tt = 0; tt < 2; ++tt) {
        const ushort_t* qp = Qb + base +
            (size_t)(qt * 128 + wave * 32 + tt * 16 + cc) * HSZ + q * 8;
        qf[tt][0] = *(const short8*)qp;
        qf[tt][1] = *(const short8*)(qp + 32);
    }

    int koff[4][2], poff[2][2];
    #pragma unroll
    for (int ut = 0; ut < 4; ++ut)
        #pragma unroll
        for (int kt = 0; kt < 2; ++kt)
            koff[ut][kt] = (ut * 16 + cc) * 64 + (((kt * 4 + q) ^ (cc & 7)) * 8);
    #pragma unroll
    for (int tt = 0; tt < 2; ++tt)
        #pragma unroll
        for (int kt = 0; kt < 2; ++kt)
            poff[tt][kt] = (tt * 16 + cc) * 72 + kt * 32 + q * 8;

    float4v oacc[2][4];
    #pragma unroll
    for (int tt = 0; tt < 2; ++tt)
        #pragma unroll
        for (int st = 0; st < 4; ++st) oacc[tt][st] = (float4v){0.f, 0.f, 0.f, 0.f};
    float lsum[2] = {0.f, 0.f};

    #pragma unroll
    for (int i = 0; i < 2; ++i) {
        async16(kg[i], &Ks[0][dmo[i]]);
        async16(vg[i], &VTs[0][dmo[i]]);
    }
    __syncthreads();

    for (int jt = 0; jt < J; ++jt) {
        const ushort_t* Kc = Ks[jt & 1];
        const ushort_t* Vc = VTs[jt & 1];
        if (jt + 1 < J) {
            int nb = (jt + 1) & 1;
            #pragma unroll
            for (int i = 0; i < 2; ++i) {
                async16(kg[i] + (size_t)(jt + 1) * 64 * HSZ, &Ks[nb][dmo[i]]);
                async16(vg[i] + (jt + 1) * 64, &VTs[nb][dmo[i]]);
            }
        }

        float4v sc[4][2];
        #pragma unroll
        for (int ut = 0; ut < 4; ++ut)
            #pragma unroll
            for (int tt = 0; tt < 2; ++tt) sc[ut][tt] = (float4v){0.f, 0.f, 0.f, 0.f};
        #pragma unroll
        for (int kt = 0; kt < 2; ++kt) {
            short8 kf[4];
            #pragma unroll
            for (int ut = 0; ut < 4; ++ut) kf[ut] = *(const short8*)(Kc + koff[ut][kt]);
            #pragma unroll
            for (int ut = 0; ut < 4; ++ut) {
                sc[ut][0] = __builtin_amdgcn_mfma_f32_16x16x32_bf16(
                    kf[ut], qf[0][kt], sc[ut][0], 0, 0, 0);
                sc[ut][1] = __builtin_amdgcn_mfma_f32_16x16x32_bf16(
                    kf[ut], qf[1][kt], sc[ut][1], 0, 0, 0);
            }
        }

        if ((jt >> 1) == qt) {   // diagonal tiles: masked path
            #pragma unroll
            for (int tt = 0; tt < 2; ++tt) {
                const int tg = qt * 128 + wave * 32 + tt * 16 + cc;
                #pragma unroll
                for (int ut = 0; ut < 4; ++ut) {
                    float pv[4]; float ps = 0.f;
                    #pragma unroll
                    for (int rr = 0; rr < 4; ++rr) {
                        float p = exp2f(sc[ut][tt][rr]);
                        if ((jt * 64 + ut * 16 + q * 4 + rr) > tg) p = 0.f;
                        pv[rr] = p; ps += p;
                    }
                    lsum[tt] += ps;
                    *(uint2*)&Ps[wave][(tt * 16 + cc) * 72 + ut * 16 + q * 4] =
                        make_uint2(pack_bf2(pv[0], pv[1]), pack_bf2(pv[2], pv[3]));
                }
            }
        } else {                 // interior tiles: no mask
            #pragma unroll
            for (int tt = 0; tt < 2; ++tt) {
                #pragma unroll
                for (int ut = 0; ut < 4; ++ut) {
                    float pv[4]; float ps = 0.f;
                    #pragma unroll
                    for (int rr = 0; rr < 4; ++rr) {
                        float p = exp2f(sc[ut][tt][rr]);
                        pv[rr] = p; ps += p;
                    }
                    lsum[tt] += ps;
                    *(uint2*)&Ps[wave][(tt * 16 + cc) * 72 + ut * 16 + q * 4] =
                        make_uint2(pack_bf2(pv[0], pv[1]), pack_bf2(pv[2], pv[3]));
                }
            }
        }

        #pragma unroll
        for (int kt = 0; kt < 2; ++kt) {
            short8 pa0 = *(const short8*)&Ps[wave][poff[0][kt]];
            short8 pa1 = *(const short8*)&Ps[wave][poff[1][kt]];
            #pragma unroll
            for (int st = 0; st < 4; ++st) {
                short8 vf = *(const short8*)(Vc + koff[st][kt]);
                oacc[0][st] = __builtin_amdgcn_mfma_f32_16x16x32_bf16(
                    pa0, vf, oacc[0][st], 0, 0, 0);
                oacc[1][st] = __builtin_amdgcn_mfma_f32_16x16x32_bf16(
                    pa1, vf, oacc[1][st], 0, 0, 0);
            }
        }
        __syncthreads();
    }

    float inv[2];
    #pragma unroll
    for (int tt = 0; tt < 2; ++tt) {
        float l = lsum[tt];
        l += __shfl_xor(l, 16);
        l += __shfl_xor(l, 32);
        inv[tt] = 1.f / l;
    }
    const int b = bh >> 4, h = bh & 15;
    #pragma unroll
    for (int tt = 0; tt < 2; ++tt)
        #pragma unroll
        for (int rr = 0; rr < 4; ++rr) {
            float iv = __shfl(inv[tt], q * 4 + rr);
            int t = qt * 128 + wave * 32 + tt * 16 + q * 4 + rr;
            size_t rb = ((size_t)b * TSEQ + t) * DMODEL + h * HSZ;
            #pragma unroll
            for (int st = 0; st < 4; ++st)
                Ob[rb + st * 16 + cc] = f2bf_fast(oacc[tt][st][rr] * iv);
        }
}

// ---------------------------------------------------------------------------
// oproj_gemm: out[m][n] = sum_k Ob[m][k]*Wob[n][k] + bo[n]. m97 structure.
// XCD m-banding: per-XCD 8 m-blocks (2 MB Ob) + Wob 2 MB -> 4 MB, L2-resident.
// grid 512.
// ---------------------------------------------------------------------------
__global__ __launch_bounds__(256) void oproj_gemm(
    const ushort_t* __restrict__ Obuf, const ushort_t* __restrict__ Wob,
    const float* __restrict__ bo, float* __restrict__ out)
{
    __shared__ ushort_t As[128 * 64];
    __shared__ ushort_t Bs[128 * 64];
    const int tid = threadIdx.x;
    const int wave = tid >> 6, lane = tid & 63;
    const int q = lane >> 4, cc = lane & 15;
    const int bid = blockIdx.x;
    const int xcd = bid & 7, local = bid >> 3;
    const int n0 = (local >> 3) * 128;
    const int m0 = (xcd * 8 + (local & 7)) * 128;
    const int wm = wave >> 1, wn = wave & 1;

    const ushort_t* ag[4]; const ushort_t* bg[4]; int lo_[4];
    #pragma unroll
    for (int i = 0; i < 4; ++i) {
        int row = wave * 32 + i * 8 + (lane >> 3);
        int ch = (lane & 7) ^ (row & 7);
        ag[i] = Obuf + (size_t)(m0 + row) * DMODEL + ch * 8;
        bg[i] = Wob + (size_t)(n0 + row) * DMODEL + ch * 8;
        lo_[i] = (wave * 32 + i * 8) * 64;
    }
    int aoff[4][2], boff[4][2];
    #pragma unroll
    for (int mt = 0; mt < 4; ++mt) {
        int row = wm * 64 + mt * 16 + cc;
        #pragma unroll
        for (int kt = 0; kt < 2; ++kt)
            aoff[mt][kt] = row * 64 + (((kt * 4 + q) ^ (row & 7)) * 8);
    }
    #pragma unroll
    for (int nt = 0; nt < 4; ++nt) {
        int row = wn * 64 + nt * 16 + cc;
        #pragma unroll
        for (int kt = 0; kt < 2; ++kt)
            boff[nt][kt] = row * 64 + (((kt * 4 + q) ^ (row & 7)) * 8);
    }

    float4v acc[4][4];
    #pragma unroll
    for (int a = 0; a < 4; ++a)
        #pragma unroll
        for (int b = 0; b < 4; ++b) acc[a][b] = (float4v){0.f, 0.f, 0.f, 0.f};

    for (int j = 0; j < 16; ++j) {
        #pragma unroll
        for (int i = 0; i < 4; ++i) {
            async16(ag[i], As + lo_[i]);
            async16(bg[i], Bs + lo_[i]);
            ag[i] += 64; bg[i] += 64;
        }
        __syncthreads();

        short8 av[4][2], bv[4][2];
        #pragma unroll
        for (int mt = 0; mt < 4; ++mt) {
            av[mt][0] = *(const short8*)(As + aoff[mt][0]);
            av[mt][1] = *(const short8*)(As + aoff[mt][1]);
        }
        #pragma unroll
        for (int nt = 0; nt < 4; ++nt) {
            bv[nt][0] = *(const short8*)(Bs + boff[nt][0]);
            bv[nt][1] = *(const short8*)(Bs + boff[nt][1]);
        }
        #pragma unroll
        for (int kt = 0; kt < 2; ++kt)
            #pragma unroll
            for (int mt = 0; mt < 4; ++mt)
                #pragma unroll
                for (int nt = 0; nt < 4; ++nt)
                    acc[mt][nt] = __builtin_amdgcn_mfma_f32_16x16x32_bf16(
                        av[mt][kt], bv[nt][kt], acc[mt][nt], 0, 0, 0);
        __syncthreads();
    }

    #pragma unroll
    for (int nt = 0; nt < 4; ++nt) {
        int n = n0 + wn * 64 + nt * 16 + cc;
        float bias = bo[n];
        #pragma unroll
        for (int mt = 0; mt < 4; ++mt)
            #pragma unroll
            for (int rr = 0; rr < 4; ++rr) {
                int m = m0 + wm * 64 + mt * 16 + q * 4 + rr;
                out[(size_t)m * DMODEL + n] = acc[mt][nt][rr] + bias;
            }
    }
}

// ---------------------------------------------------------------------------
extern "C" void kernel_launch(void* const* d_in, const int* in_sizes, int n_in,
                              void* d_out, int out_size, void* d_ws, size_t ws_size,
                              hipStream_t stream)
{
    const float* x  = (const float*)d_in[0];
    const float* Wq = (const float*)d_in[1];
    const float* Wk = (const float*)d_in[2];
    const float* Wv = (const float*)d_in[3];
    const float* Wo = (const float*)d_in[4];
    const float* bo = (const float*)d_in[5];
    float* out = (float*)d_out;

    // ws (64MB): [0,16M) Qb (->Wob after attn)  [16,32) Kb  [32,48) Vt
    //            [48,64) WpT (first 6MB, dead after qkv) -> Ob (attn output)
    // Xb (bf16 X, 16MB) in d_out's first half (dead before oproj writes out).
    const size_t SEG = (size_t)8 * 1024 * 1024;
    ushort_t* Qb  = (ushort_t*)d_ws;
    ushort_t* Kb  = Qb + SEG;
    ushort_t* Vtb = Kb + SEG;
    ushort_t* WpT = Vtb + SEG;
    ushort_t* Ob  = WpT;         // WpT dead after qkv_gemm
    ushort_t* Xb  = (ushort_t*)d_out;
    ushort_t* Wob = Qb;          // Qb dead after attn

    cvt_f32_bf16<<<dim3(2048),    256, 0, stream>>>(x, Xb);
    pack_w      <<<dim3(16, 48),  256, 0, stream>>>(Wq, Wk, Wv, WpT);
    qkv_gemm    <<<dim3(768),     512, 0, stream>>>(Xb, WpT, Qb, Kb, Vtb);
    attn        <<<dim3(1024),    256, 0, stream>>>(Qb, Kb, Vtb, Ob);
    cvt_f32_bf16<<<dim3(256),     256, 0, stream>>>(Wo, Wob);
    oproj_gemm  <<<dim3(512),     256, 0, stream>>>(Ob, Wob, bo, out);
}

// Round 4
// 223.780 us; speedup vs baseline: 1.1345x; 1.0331x over previous
//
#include <hip/hip_runtime.h>
#include <hip/hip_bf16.h>

#define BBATCH 8
#define TSEQ   1024
#define DMODEL 1024
#define NHEAD  16
#define HSZ    64

typedef unsigned short ushort_t;
typedef __attribute__((ext_vector_type(8))) short short8;
typedef __attribute__((ext_vector_type(4))) float float4v;

__device__ __forceinline__ ushort_t f2bf(float f) {
    __hip_bfloat16 h = __float2bfloat16(f);
    return *reinterpret_cast<ushort_t*>(&h);
}
// fast fp32->bf16, round-half-up
__device__ __forceinline__ ushort_t f2bf_fast(float f) {
    return (ushort_t)((__float_as_uint(f) + 0x8000u) >> 16);
}
// pack two fp32 -> uint {bf16(lo), bf16(hi)}
__device__ __forceinline__ unsigned int pack_bf2(float lo, float hi) {
    unsigned int a = __float_as_uint(lo) + 0x8000u;
    unsigned int b = __float_as_uint(hi) + 0x8000u;
    return __builtin_amdgcn_perm(b, a, 0x07060302u);
}

__device__ __forceinline__ short8 cvt8(const float* f) {
    union { ushort_t u[8]; short8 v; } r;
    #pragma unroll
    for (int e = 0; e < 8; ++e) r.u[e] = f2bf(f[e]);
    return r.v;
}

// async global->LDS, 16B/lane; lds base wave-uniform (HW: base + lane*16)
__device__ __forceinline__ void async16(const ushort_t* g, ushort_t* l) {
    __builtin_amdgcn_global_load_lds(
        (const __attribute__((address_space(1))) unsigned int*)g,
        (__attribute__((address_space(3))) unsigned int*)l, 16, 0, 0);
}

template<int N> __device__ __forceinline__ void vwait() {
    if constexpr (N == 6)      asm volatile("s_waitcnt vmcnt(6)" ::: "memory");
    else if constexpr (N == 3) asm volatile("s_waitcnt vmcnt(3)" ::: "memory");
    else if constexpr (N == 0) asm volatile("s_waitcnt vmcnt(0)" ::: "memory");
    // N < 0: no wait
}

// ---------------------------------------------------------------------------
// cvt_f32_bf16: generic fp32 -> bf16, 16 elems/thread (X, Wo)
// ---------------------------------------------------------------------------
__global__ __launch_bounds__(256) void cvt_f32_bf16(
    const float* __restrict__ src, ushort_t* __restrict__ dst)
{
    const size_t idx = ((size_t)blockIdx.x * 256 + threadIdx.x) * 16;
    float f[16];
    *(float4*)(f + 0)  = *(const float4*)(src + idx);
    *(float4*)(f + 4)  = *(const float4*)(src + idx + 4);
    *(float4*)(f + 8)  = *(const float4*)(src + idx + 8);
    *(float4*)(f + 12) = *(const float4*)(src + idx + 12);
    uint4 o0 = make_uint4(pack_bf2(f[0], f[1]),   pack_bf2(f[2], f[3]),
                          pack_bf2(f[4], f[5]),   pack_bf2(f[6], f[7]));
    uint4 o1 = make_uint4(pack_bf2(f[8], f[9]),   pack_bf2(f[10], f[11]),
                          pack_bf2(f[12], f[13]), pack_bf2(f[14], f[15]));
    *(uint4*)(dst + idx) = o0;
    *(uint4*)(dst + idx + 8) = o1;
}

// ---------------------------------------------------------------------------
// pack_w: WpackT[w*1024 + h*64 + s][d] = W_w[h][d][s]  (fp32 -> bf16, n-major)
// ---------------------------------------------------------------------------
__global__ __launch_bounds__(256) void pack_w(
    const float* __restrict__ Wq, const float* __restrict__ Wk,
    const float* __restrict__ Wv, ushort_t* __restrict__ WpT)
{
    __shared__ ushort_t L[64 * 72];
    const int tid = threadIdx.x;
    const int d0 = blockIdx.x * 64;
    const int wh = blockIdx.y;
    const int w = wh >> 4, h = wh & 15;
    const float* W = (w == 0 ? Wq : (w == 1 ? Wk : Wv)) + (size_t)h * DMODEL * HSZ;

    int dr = tid >> 2, sc = (tid & 3) * 16;
    const float4* src = (const float4*)(W + (size_t)(d0 + dr) * HSZ + sc);
    float f[16];
    *(float4*)(f + 0) = src[0]; *(float4*)(f + 4) = src[1];
    *(float4*)(f + 8) = src[2]; *(float4*)(f + 12) = src[3];
    *(short8*)(L + dr * 72 + sc)     = cvt8(f);
    *(short8*)(L + dr * 72 + sc + 8) = cvt8(f + 8);
    __syncthreads();

    int s = tid >> 2, dc = (tid & 3) * 16;
    union { ushort_t u[16]; short8 v[2]; } o;
    #pragma unroll
    for (int j = 0; j < 16; ++j) o.u[j] = L[(dc + j) * 72 + s];
    ushort_t* dst = WpT + (size_t)(w * 1024 + h * 64 + s) * DMODEL + d0 + dc;
    *(short8*)dst = o.v[0];
    *(short8*)(dst + 8) = o.v[1];
}

// ---------------------------------------------------------------------------
// qkv_gemm: 128(A-rows) x 256(B-rows) tiles, BK=32, 4 waves (1x4, 256 thr),
// TRIPLE-buffered LDS (72KB -> 2 blocks/CU), ONE barrier per K-step,
// counted vmcnt(6), per-wave 128x64 output (32 MFMA/step).
//
// Per K-step t (identical every step):
//   12x ds_read_b128 (A a0-7 full 128 rows, B b0-3 own 64 rows)
//   6x global_load_lds -> buf[(t+2)%3]  (A: 2 instr, B: 4 instr per wave)
//   setprio(1); 32 MFMA; setprio(0)
//   s_waitcnt vmcnt(6)   // confirms buf[(t+1)%3] landed (prev step's 6)
//   s_barrier            // single barrier: bounds wave skew to 1 step
//
// LDS traffic/step/block: reads 4xA(8K)+1xB... = 48KB (was 64KB at 8 waves),
// writes 24KB; 2-way-clean swizzle (was 4-way conflicted):
//   stage src chunk = (lane&3) ^ ((lane>>3)&3)  [= (row>>1)&3 involution]
//   read  chunk     = q ^ ((cc>>1)&3)
//   bank = 16*(row&1) + 4*chunk -> 16 lanes cover 8 bank-groups exactly 2x.
// Grid 768 = 512 QK + 256 V uniform blocks -> exactly 3 rounds at 2/CU.
// QK: A = W rows (s), B = X rows (t) -> out[s][t] -> Qb/Kb[bh][t][s].
// V:  A = X rows (t), B = Wv rows (s) -> out[t][s] -> Vt[bh][s][t].
// Q pre-scaled by 0.125*log2(e).
// ---------------------------------------------------------------------------
template<bool STG, int VW>
__device__ __forceinline__ void kstep32(
    const ushort_t* Ab, const ushort_t* Bb,     // read buffers (step t)
    ushort_t* An, ushort_t* Bn,                 // stage buffers (step t+2)
    const ushort_t*& gA, const ushort_t*& gB,   // advance +32 when STG
    const int wave,
    const int (&aoff)[8], const int (&boff)[4],
    float4v (&acc)[8][4])
{
    short8 av[8], bv[4];
    #pragma unroll
    for (int a = 0; a < 8; ++a) av[a] = *(const short8*)(Ab + aoff[a]);
    #pragma unroll
    for (int b = 0; b < 4; ++b) bv[b] = *(const short8*)(Bb + boff[b]);
    if (STG) {
        async16(gA,                An + (wave)     * 512);
        async16(gA + 64 * DMODEL,  An + (wave + 4) * 512);
        async16(gB,                Bn + (wave)     * 512);
        async16(gB + 64 * DMODEL,  Bn + (wave + 4) * 512);
        async16(gB + 128 * DMODEL, Bn + (wave + 8) * 512);
        async16(gB + 192 * DMODEL, Bn + (wave + 12) * 512);
        gA += 32; gB += 32;
    }
    __builtin_amdgcn_s_setprio(1);
    #pragma unroll
    for (int a = 0; a < 8; ++a)
        #pragma unroll
        for (int b = 0; b < 4; ++b)
            acc[a][b] = __builtin_amdgcn_mfma_f32_16x16x32_bf16(
                av[a], bv[b], acc[a][b], 0, 0, 0);
    __builtin_amdgcn_s_setprio(0);
    vwait<VW>();
    __builtin_amdgcn_s_barrier();
}

__global__ __launch_bounds__(256, 2) void qkv_gemm(
    const ushort_t* __restrict__ Xb, const ushort_t* __restrict__ WpT,
    ushort_t* __restrict__ Qb, ushort_t* __restrict__ Kb, ushort_t* __restrict__ Vt)
{
    __shared__ ushort_t Ab[3][128 * 32];   // 3 x 8KB
    __shared__ ushort_t Bb[3][256 * 32];   // 3 x 16KB  -> 72KB total

    const int tid = threadIdx.x;
    const int wave = tid >> 6, lane = tid & 63;
    const int q = lane >> 4, cc = lane & 15;

    // block -> tile. QK: bid 0..511; V: bid 512..767. xcd = bid & 7.
    const int bid = blockIdx.x;
    const int xcd = bid & 7;
    const bool isV = (bid >= 512);
    int ta, tb;    // A-tile (128 rows), B-tile (256 rows)
    if (!isV) {
        int lo = bid >> 3;            // 0..63
        ta = lo >> 2;                 // W n-tile 0..15 (ta<8: Q, else K)
        tb = xcd * 4 + (lo & 3);      // X m-tile 0..31 (XCD band: 2MB)
    } else {
        int lo = (bid - 512) >> 3;    // 0..31
        ta = xcd * 8 + (lo & 7);      // X m-tile 0..63 (XCD band: 2MB)
        tb = lo >> 3;                 // Wv n-tile 0..3
    }
    const ushort_t* pA = isV ? Xb  + (size_t)ta * 128 * DMODEL
                             : WpT + (size_t)ta * 128 * DMODEL;
    const ushort_t* pB = isV ? WpT + (size_t)(2048 + tb * 256) * DMODEL
                             : Xb  + (size_t)tb * 256 * DMODEL;

    // staging source addrs: per instr, wave covers 16 rows x 64B; source
    // chunk pre-swizzled so linear LDS holds LDS[r][c] = glob[r][c^((r>>1)&3)]
    const int srow = lane >> 2;                          // 0..15 row-in-group
    const int chx = (lane & 3) ^ ((lane >> 3) & 3);      // = (row>>1)&3 XOR
    const ushort_t* gA = pA + (size_t)(wave * 16 + srow) * DMODEL + chx * 8;
    const ushort_t* gB = pB + (size_t)(wave * 16 + srow) * DMODEL + chx * 8;

    // ds_read offsets (elems): A frag f: row = f*16+cc (f=0..7, all 128 rows)
    //                          B frag f: row = wave*64 + f*16 + cc (f=0..3)
    // chunk = q ^ ((cc>>1)&3): (row&1, chunk) covers 8 bank-groups 2x = free
    int aoff[8], boff[4];
    const int cswz = (q ^ ((cc >> 1) & 3)) * 8;
    #pragma unroll
    for (int f = 0; f < 8; ++f)
        aoff[f] = (f * 16 + cc) * 32 + cswz;
    #pragma unroll
    for (int f = 0; f < 4; ++f)
        boff[f] = (wave * 64 + f * 16 + cc) * 32 + cswz;

    float4v acc[8][4];
    #pragma unroll
    for (int a = 0; a < 8; ++a)
        #pragma unroll
        for (int b = 0; b < 4; ++b) acc[a][b] = (float4v){0.f, 0.f, 0.f, 0.f};

    // prologue: stage t0 -> buf0, t1 -> buf1; confirm t0; barrier
    async16(gA,                Ab[0] + (wave)     * 512);
    async16(gA + 64 * DMODEL,  Ab[0] + (wave + 4) * 512);
    async16(gB,                Bb[0] + (wave)     * 512);
    async16(gB + 64 * DMODEL,  Bb[0] + (wave + 4) * 512);
    async16(gB + 128 * DMODEL, Bb[0] + (wave + 8) * 512);
    async16(gB + 192 * DMODEL, Bb[0] + (wave + 12) * 512);
    gA += 32; gB += 32;
    async16(gA,                Ab[1] + (wave)     * 512);
    async16(gA + 64 * DMODEL,  Ab[1] + (wave + 4) * 512);
    async16(gB,                Bb[1] + (wave)     * 512);
    async16(gB + 64 * DMODEL,  Bb[1] + (wave + 4) * 512);
    async16(gB + 128 * DMODEL, Bb[1] + (wave + 8) * 512);
    async16(gB + 192 * DMODEL, Bb[1] + (wave + 12) * 512);
    gA += 32; gB += 32;
    vwait<6>();
    __builtin_amdgcn_s_barrier();

    // 32 K-steps: 30 steady (stage t+2, vmcnt(6)), then t30 (vmcnt 0), t31
    #pragma unroll 1
    for (int it = 0; it < 10; ++it) {
        kstep32<true, 6>(Ab[0], Bb[0], Ab[2], Bb[2], gA, gB, wave, aoff, boff, acc);
        kstep32<true, 6>(Ab[1], Bb[1], Ab[0], Bb[0], gA, gB, wave, aoff, boff, acc);
        kstep32<true, 6>(Ab[2], Bb[2], Ab[1], Bb[1], gA, gB, wave, aoff, boff, acc);
    }
    kstep32<false, 0>(Ab[0], Bb[0], Ab[2], Bb[2], gA, gB, wave, aoff, boff, acc);
    kstep32<false, -1>(Ab[1], Bb[1], Ab[0], Bb[0], gA, gB, wave, aoff, boff, acc);

    // epilogue: out[rowA = ta*128 + a*16 + q*4+rr][colB = tb*256 + wave*64
    // + b*16 + cc]; inner loop a -> stores land in 1-2 contiguous 128B lines
    if (!isV) {
        ushort_t* Out = (ta < 8) ? Qb : Kb;
        const float osc = (ta < 8) ? 0.18033688011112042f : 1.0f;
        #pragma unroll
        for (int b = 0; b < 4; ++b) {
            int mc = tb * 256 + wave * 64 + b * 16 + cc;    // t (col)
            int bb = mc >> 10, t = mc & 1023;
            #pragma unroll
            for (int a = 0; a < 8; ++a) {
                int srw = ta * 128 + a * 16 + q * 4;        // s-row in [0,2048)
                int h = (srw >> 6) & 15, s0 = srw & 63;
                size_t addr = (((size_t)(bb * NHEAD + h)) * TSEQ + t) * HSZ + s0;
                uint2 pk = make_uint2(
                    pack_bf2(acc[a][b][0] * osc, acc[a][b][1] * osc),
                    pack_bf2(acc[a][b][2] * osc, acc[a][b][3] * osc));
                *(uint2*)(Out + addr) = pk;
            }
        }
    } else {
        #pragma unroll
        for (int b = 0; b < 4; ++b) {
            int nc = tb * 256 + wave * 64 + b * 16 + cc;    // s (col), 0..1023
            int h = nc >> 6, s = nc & 63;
            #pragma unroll
            for (int a = 0; a < 8; ++a) {
                int mr = ta * 128 + a * 16 + q * 4;         // t (row)
                int bb = mr >> 10, t0 = mr & 1023;
                size_t addr = (((size_t)(bb * NHEAD + h)) * HSZ + s) * TSEQ + t0;
                uint2 pk = make_uint2(pack_bf2(acc[a][b][0], acc[a][b][1]),
                                      pack_bf2(acc[a][b][2], acc[a][b][3]));
                *(uint2*)(Vt + addr) = pk;
            }
        }
    }
}

// ---------------------------------------------------------------------------
// attn: flash attention, Q-tile 128, KV-tile 64, dbuf DMA prefetch, exp2
// softmax without running max; causal mask only on the 2 diagonal jt-tiles
// (wave-uniform branch). 1-D grid 1024, bid&7 == bh&7 -> per-bh KV co-XCD.
// ---------------------------------------------------------------------------
__global__ __launch_bounds__(256) void attn(
    const ushort_t* __restrict__ Qb, const ushort_t* __restrict__ Kb,
    const ushort_t* __restrict__ Vt, ushort_t* __restrict__ Ob)
{
    __shared__ ushort_t Ks[2][64 * 64];
    __shared__ ushort_t VTs[2][64 * 64];
    __shared__ ushort_t Ps[4][32 * 72];
    const int tid = threadIdx.x;
    const int wave = tid >> 6, lane = tid & 63;
    const int q = lane >> 4, cc = lane & 15;
    const int bid = blockIdx.x;
    const int qt = 7 - (bid >> 7);    // big-J blocks first
    const int bh = bid & 127;
    const size_t base = (size_t)bh * TSEQ * HSZ;
    const int J = 2 * qt + 2;

    const ushort_t* kg[2]; const ushort_t* vg[2]; int dmo[2];
    #pragma unroll
    for (int i = 0; i < 2; ++i) {
        int rr = wave * 16 + i * 8 + (lane >> 3);
        int ch = (lane & 7) ^ (rr & 7);
        kg[i] = Kb + base + (size_t)rr * HSZ + ch * 8;
        vg[i] = Vt + base + (size_t)rr * TSEQ + ch * 8;
        dmo[i] = (wave * 16 + i * 8) * 64;
    }

    short8 qf[2][2];
    #pragma unroll
    for (int tt = 0; tt < 2; ++tt) {
        const ushort_t* qp = Qb + base +
            (size_t)(qt * 128 + wave * 32 + tt * 16 + cc) * HSZ + q * 8;
        qf[tt][0] = *(const short8*)qp;
        qf[tt][1] = *(const short8*)(qp + 32);
    }

    int koff[4][2], poff[2][2];
    #pragma unroll
    for (int ut = 0; ut < 4; ++ut)
        #pragma unroll
        for (int kt = 0; kt < 2; ++kt)
            koff[ut][kt] = (ut * 16 + cc) * 64 + (((kt * 4 + q) ^ (cc & 7)) * 8);
    #pragma unroll
    for (int tt = 0; tt < 2; ++tt)
        #pragma unroll
        for (int kt = 0; kt < 2; ++kt)
            poff[tt][kt] = (tt * 16 + cc) * 72 + kt * 32 + q * 8;

    float4v oacc[2][4];
    #pragma unroll
    for (int tt = 0; tt < 2; ++tt)
        #pragma unroll
        for (int st = 0; st < 4; ++st) oacc[tt][st] = (float4v){0.f, 0.f, 0.f, 0.f};
    float lsum[2] = {0.f, 0.f};

    #pragma unroll
    for (int i = 0; i < 2; ++i) {
        async16(kg[i], &Ks[0][dmo[i]]);
        async16(vg[i], &VTs[0][dmo[i]]);
    }
    __syncthreads();

    for (int jt = 0; jt < J; ++jt) {
        const ushort_t* Kc = Ks[jt & 1];
        const ushort_t* Vc = VTs[jt & 1];
        if (jt + 1 < J) {
            int nb = (jt + 1) & 1;
            #pragma unroll
            for (int i = 0; i < 2; ++i) {
                async16(kg[i] + (size_t)(jt + 1) * 64 * HSZ, &Ks[nb][dmo[i]]);
                async16(vg[i] + (jt + 1) * 64, &VTs[nb][dmo[i]]);
            }
        }

        float4v sc[4][2];
        #pragma unroll
        for (int ut = 0; ut < 4; ++ut)
            #pragma unroll
            for (int tt = 0; tt < 2; ++tt) sc[ut][tt] = (float4v){0.f, 0.f, 0.f, 0.f};
        #pragma unroll
        for (int kt = 0; kt < 2; ++kt) {
            short8 kf[4];
            #pragma unroll
            for (int ut = 0; ut < 4; ++ut) kf[ut] = *(const short8*)(Kc + koff[ut][kt]);
            #pragma unroll
            for (int ut = 0; ut < 4; ++ut) {
                sc[ut][0] = __builtin_amdgcn_mfma_f32_16x16x32_bf16(
                    kf[ut], qf[0][kt], sc[ut][0], 0, 0, 0);
                sc[ut][1] = __builtin_amdgcn_mfma_f32_16x16x32_bf16(
                    kf[ut], qf[1][kt], sc[ut][1], 0, 0, 0);
            }
        }

        if ((jt >> 1) == qt) {   // diagonal tiles: masked path
            #pragma unroll
            for (int tt = 0; tt < 2; ++tt) {
                const int tg = qt * 128 + wave * 32 + tt * 16 + cc;
                #pragma unroll
                for (int ut = 0; ut < 4; ++ut) {
                    float pv[4]; float ps = 0.f;
                    #pragma unroll
                    for (int rr = 0; rr < 4; ++rr) {
                        float p = exp2f(sc[ut][tt][rr]);
                        if ((jt * 64 + ut * 16 + q * 4 + rr) > tg) p = 0.f;
                        pv[rr] = p; ps += p;
                    }
                    lsum[tt] += ps;
                    *(uint2*)&Ps[wave][(tt * 16 + cc) * 72 + ut * 16 + q * 4] =
                        make_uint2(pack_bf2(pv[0], pv[1]), pack_bf2(pv[2], pv[3]));
                }
            }
        } else {                 // interior tiles: no mask
            #pragma unroll
            for (int tt = 0; tt < 2; ++tt) {
                #pragma unroll
                for (int ut = 0; ut < 4; ++ut) {
                    float pv[4]; float ps = 0.f;
                    #pragma unroll
                    for (int rr = 0; rr < 4; ++rr) {
                        float p = exp2f(sc[ut][tt][rr]);
                        pv[rr] = p; ps += p;
                    }
                    lsum[tt] += ps;
                    *(uint2*)&Ps[wave][(tt * 16 + cc) * 72 + ut * 16 + q * 4] =
                        make_uint2(pack_bf2(pv[0], pv[1]), pack_bf2(pv[2], pv[3]));
                }
            }
        }

        #pragma unroll
        for (int kt = 0; kt < 2; ++kt) {
            short8 pa0 = *(const short8*)&Ps[wave][poff[0][kt]];
            short8 pa1 = *(const short8*)&Ps[wave][poff[1][kt]];
            #pragma unroll
            for (int st = 0; st < 4; ++st) {
                short8 vf = *(const short8*)(Vc + koff[st][kt]);
                oacc[0][st] = __builtin_amdgcn_mfma_f32_16x16x32_bf16(
                    pa0, vf, oacc[0][st], 0, 0, 0);
                oacc[1][st] = __builtin_amdgcn_mfma_f32_16x16x32_bf16(
                    pa1, vf, oacc[1][st], 0, 0, 0);
            }
        }
        __syncthreads();
    }

    float inv[2];
    #pragma unroll
    for (int tt = 0; tt < 2; ++tt) {
        float l = lsum[tt];
        l += __shfl_xor(l, 16);
        l += __shfl_xor(l, 32);
        inv[tt] = 1.f / l;
    }
    const int b = bh >> 4, h = bh & 15;
    #pragma unroll
    for (int tt = 0; tt < 2; ++tt)
        #pragma unroll
        for (int rr = 0; rr < 4; ++rr) {
            float iv = __shfl(inv[tt], q * 4 + rr);
            int t = qt * 128 + wave * 32 + tt * 16 + q * 4 + rr;
            size_t rb = ((size_t)b * TSEQ + t) * DMODEL + h * HSZ;
            #pragma unroll
            for (int st = 0; st < 4; ++st)
                Ob[rb + st * 16 + cc] = f2bf_fast(oacc[tt][st][rr] * iv);
        }
}

// ---------------------------------------------------------------------------
// oproj_gemm: out[m][n] = sum_k Ob[m][k]*Wob[n][k] + bo[n]. m97 structure.
// XCD m-banding: per-XCD 8 m-blocks (2 MB Ob) + Wob 2 MB -> 4 MB, L2-resident.
// grid 512.
// ---------------------------------------------------------------------------
__global__ __launch_bounds__(256) void oproj_gemm(
    const ushort_t* __restrict__ Obuf, const ushort_t* __restrict__ Wob,
    const float* __restrict__ bo, float* __restrict__ out)
{
    __shared__ ushort_t As[128 * 64];
    __shared__ ushort_t Bs[128 * 64];
    const int tid = threadIdx.x;
    const int wave = tid >> 6, lane = tid & 63;
    const int q = lane >> 4, cc = lane & 15;
    const int bid = blockIdx.x;
    const int xcd = bid & 7, local = bid >> 3;
    const int n0 = (local >> 3) * 128;
    const int m0 = (xcd * 8 + (local & 7)) * 128;
    const int wm = wave >> 1, wn = wave & 1;

    const ushort_t* ag[4]; const ushort_t* bg[4]; int lo_[4];
    #pragma unroll
    for (int i = 0; i < 4; ++i) {
        int row = wave * 32 + i * 8 + (lane >> 3);
        int ch = (lane & 7) ^ (row & 7);
        ag[i] = Obuf + (size_t)(m0 + row) * DMODEL + ch * 8;
        bg[i] = Wob + (size_t)(n0 + row) * DMODEL + ch * 8;
        lo_[i] = (wave * 32 + i * 8) * 64;
    }
    int aoff[4][2], boff[4][2];
    #pragma unroll
    for (int mt = 0; mt < 4; ++mt) {
        int row = wm * 64 + mt * 16 + cc;
        #pragma unroll
        for (int kt = 0; kt < 2; ++kt)
            aoff[mt][kt] = row * 64 + (((kt * 4 + q) ^ (row & 7)) * 8);
    }
    #pragma unroll
    for (int nt = 0; nt < 4; ++nt) {
        int row = wn * 64 + nt * 16 + cc;
        #pragma unroll
        for (int kt = 0; kt < 2; ++kt)
            boff[nt][kt] = row * 64 + (((kt * 4 + q) ^ (row & 7)) * 8);
    }

    float4v acc[4][4];
    #pragma unroll
    for (int a = 0; a < 4; ++a)
        #pragma unroll
        for (int b = 0; b < 4; ++b) acc[a][b] = (float4v){0.f, 0.f, 0.f, 0.f};

    for (int j = 0; j < 16; ++j) {
        #pragma unroll
        for (int i = 0; i < 4; ++i) {
            async16(ag[i], As + lo_[i]);
            async16(bg[i], Bs + lo_[i]);
            ag[i] += 64; bg[i] += 64;
        }
        __syncthreads();

        short8 av[4][2], bv[4][2];
        #pragma unroll
        for (int mt = 0; mt < 4; ++mt) {
            av[mt][0] = *(const short8*)(As + aoff[mt][0]);
            av[mt][1] = *(const short8*)(As + aoff[mt][1]);
        }
        #pragma unroll
        for (int nt = 0; nt < 4; ++nt) {
            bv[nt][0] = *(const short8*)(Bs + boff[nt][0]);
            bv[nt][1] = *(const short8*)(Bs + boff[nt][1]);
        }
        #pragma unroll
        for (int kt = 0; kt < 2; ++kt)
            #pragma unroll
            for (int mt = 0; mt < 4; ++mt)
                #pragma unroll
                for (int nt = 0; nt < 4; ++nt)
                    acc[mt][nt] = __builtin_amdgcn_mfma_f32_16x16x32_bf16(
                        av[mt][kt], bv[nt][kt], acc[mt][nt], 0, 0, 0);
        __syncthreads();
    }

    #pragma unroll
    for (int nt = 0; nt < 4; ++nt) {
        int n = n0 + wn * 64 + nt * 16 + cc;
        float bias = bo[n];
        #pragma unroll
        for (int mt = 0; mt < 4; ++mt)
            #pragma unroll
            for (int rr = 0; rr < 4; ++rr) {
                int m = m0 + wm * 64 + mt * 16 + q * 4 + rr;
                out[(size_t)m * DMODEL + n] = acc[mt][nt][rr] + bias;
            }
    }
}

// ---------------------------------------------------------------------------
extern "C" void kernel_launch(void* const* d_in, const int* in_sizes, int n_in,
                              void* d_out, int out_size, void* d_ws, size_t ws_size,
                              hipStream_t stream)
{
    const float* x  = (const float*)d_in[0];
    const float* Wq = (const float*)d_in[1];
    const float* Wk = (const float*)d_in[2];
    const float* Wv = (const float*)d_in[3];
    const float* Wo = (const float*)d_in[4];
    const float* bo = (const float*)d_in[5];
    float* out = (float*)d_out;

    // ws (64MB): [0,16M) Qb (->Wob after attn)  [16,32) Kb  [32,48) Vt
    //            [48,64) WpT (first 6MB, dead after qkv) -> Ob (attn output)
    // Xb (bf16 X, 16MB) in d_out's first half (dead before oproj writes out).
    const size_t SEG = (size_t)8 * 1024 * 1024;
    ushort_t* Qb  = (ushort_t*)d_ws;
    ushort_t* Kb  = Qb + SEG;
    ushort_t* Vtb = Kb + SEG;
    ushort_t* WpT = Vtb + SEG;
    ushort_t* Ob  = WpT;         // WpT dead after qkv_gemm
    ushort_t* Xb  = (ushort_t*)d_out;
    ushort_t* Wob = Qb;          // Qb dead after attn

    cvt_f32_bf16<<<dim3(2048),    256, 0, stream>>>(x, Xb);
    pack_w      <<<dim3(16, 48),  256, 0, stream>>>(Wq, Wk, Wv, WpT);
    qkv_gemm    <<<dim3(768),     256, 0, stream>>>(Xb, WpT, Qb, Kb, Vtb);
    attn        <<<dim3(1024),    256, 0, stream>>>(Qb, Kb, Vtb, Ob);
    cvt_f32_bf16<<<dim3(256),     256, 0, stream>>>(Wo, Wob);
    oproj_gemm  <<<dim3(512),     256, 0, stream>>>(Ob, Wob, bo, out);
}